// Round 1
// baseline (721.585 us; speedup 1.0000x reference)
//
#include <hip/hip_runtime.h>
#include <hip/hip_bf16.h>
#include <cstdint>

#define NEGV -1e9f

// ---------------- wave helpers (wave64) ----------------
__device__ __forceinline__ float wred_sum(float v) {
#pragma unroll
  for (int o = 32; o; o >>= 1) v += __shfl_xor(v, o);
  return v;
}
__device__ __forceinline__ float wred_max(float v) {
#pragma unroll
  for (int o = 32; o; o >>= 1) v = fmaxf(v, __shfl_xor(v, o));
  return v;
}

// ---------------- fused GEMM ----------------
// out[m,n] = epilogue( sum_k A[m,k]*B[k,n] + bias[n] )
// GEMM1: A = embed[seq[m]] (gather), RELU, out=act1 (stride 512)
// GEMM2: A = act1, +embed[seq[m]][n] residual, out=X (stride 256)
template <int KDIM, int BSTRIDE, bool GATHER_A, bool RELU_, bool ADD_EMBED, int OUTSTRIDE>
__global__ __launch_bounds__(256) void gemm_k(
    const float* __restrict__ Asrc, const float* __restrict__ Bsrc,
    const float* __restrict__ bias, const float* __restrict__ embed,
    const int* __restrict__ seq, float* __restrict__ out) {
  __shared__ float As[32][68];   // transposed A tile: As[k][m]
  __shared__ float Bs[32][132];
  __shared__ int sidx[64];
  const int tid = threadIdx.x;
  const int m0 = blockIdx.x * 64;
  const int n0 = blockIdx.y * 128;
  if (GATHER_A || ADD_EMBED) {
    if (tid < 64) sidx[tid] = seq[m0 + tid];
  }
  __syncthreads();

  const int ty = tid >> 4, tx = tid & 15;
  float acc[4][8];
#pragma unroll
  for (int i = 0; i < 4; ++i)
#pragma unroll
    for (int j = 0; j < 8; ++j) acc[i][j] = 0.f;

  for (int k0 = 0; k0 < KDIM; k0 += 32) {
    // stage A: 64 rows x 32 k (512 float4, 2/thread), transposed into LDS
#pragma unroll
    for (int j = 0; j < 2; ++j) {
      int f = tid + j * 256;
      int m = f >> 3, kq = f & 7;
      const float* ap;
      if constexpr (GATHER_A)
        ap = embed + (size_t)sidx[m] * 256 + k0 + kq * 4;
      else
        ap = Asrc + (size_t)(m0 + m) * KDIM + k0 + kq * 4;
      float4 a = *(const float4*)ap;
      As[kq * 4 + 0][m] = a.x;
      As[kq * 4 + 1][m] = a.y;
      As[kq * 4 + 2][m] = a.z;
      As[kq * 4 + 3][m] = a.w;
    }
    // stage B: 32 rows x 128 (1024 float4, 4/thread)
#pragma unroll
    for (int j = 0; j < 4; ++j) {
      int f = tid + j * 256;
      int r = f >> 5, cq = f & 31;
      *(float4*)&Bs[r][cq * 4] =
          *(const float4*)(Bsrc + (size_t)(k0 + r) * BSTRIDE + n0 + cq * 4);
    }
    __syncthreads();
#pragma unroll
    for (int kk = 0; kk < 32; ++kk) {
      float4 av = *(const float4*)&As[kk][ty * 4];
      float4 b0 = *(const float4*)&Bs[kk][tx * 8];
      float4 b1v = *(const float4*)&Bs[kk][tx * 8 + 4];
      float a_[4] = {av.x, av.y, av.z, av.w};
      float b_[8] = {b0.x, b0.y, b0.z, b0.w, b1v.x, b1v.y, b1v.z, b1v.w};
#pragma unroll
      for (int i = 0; i < 4; ++i)
#pragma unroll
        for (int j = 0; j < 8; ++j) acc[i][j] += a_[i] * b_[j];
    }
    __syncthreads();
  }

  float bs[8];
#pragma unroll
  for (int j = 0; j < 8; ++j) bs[j] = bias[n0 + tx * 8 + j];
#pragma unroll
  for (int i = 0; i < 4; ++i) {
    const int m = m0 + ty * 4 + i;
    float r[8];
#pragma unroll
    for (int j = 0; j < 8; ++j) {
      float t = acc[i][j] + bs[j];
      if constexpr (RELU_) t = fmaxf(t, 0.f);
      r[j] = t;
    }
    if constexpr (ADD_EMBED) {
      const float* ep = embed + (size_t)sidx[ty * 4 + i] * 256 + n0 + tx * 8;
      float4 e0 = *(const float4*)ep;
      float4 e1 = *(const float4*)(ep + 4);
      r[0] += e0.x; r[1] += e0.y; r[2] += e0.z; r[3] += e0.w;
      r[4] += e1.x; r[5] += e1.y; r[6] += e1.z; r[7] += e1.w;
    }
    float* op = out + (size_t)m * OUTSTRIDE + n0 + tx * 8;
    float4 v0 = {r[0], r[1], r[2], r[3]};
    float4 v1 = {r[4], r[5], r[6], r[7]};
    *(float4*)op = v0;
    *(float4*)(op + 4) = v1;
  }
}

// ---------------- LayerNorm (in place) + gate/demotion precompute ----------------
__global__ __launch_bounds__(256) void ln_k(
    float* __restrict__ X, const float* __restrict__ gamma,
    const float* __restrict__ beta, const float* __restrict__ Wg,
    const float* __restrict__ bg, const float* __restrict__ Wd,
    const float* __restrict__ bd, int* __restrict__ wbit,
    float* __restrict__ dsc) {
  const int row = blockIdx.x * 4 + (threadIdx.x >> 6);
  const int lane = threadIdx.x & 63;
  float* xp = X + (size_t)row * 256 + lane * 4;
  float4 x = *(float4*)xp;
  float s = (x.x + x.y) + (x.z + x.w);
  s = wred_sum(s);
  float mu = s * (1.f / 256.f);
  float dx0 = x.x - mu, dx1 = x.y - mu, dx2 = x.z - mu, dx3 = x.w - mu;
  float v = (dx0 * dx0 + dx1 * dx1) + (dx2 * dx2 + dx3 * dx3);
  v = wred_sum(v);
  float rstd = 1.f / sqrtf(v * (1.f / 256.f) + 1e-5f);
  float4 g4 = *(const float4*)(gamma + lane * 4);
  float4 b4 = *(const float4*)(beta + lane * 4);
  float4 y;
  y.x = dx0 * rstd * g4.x + b4.x;
  y.y = dx1 * rstd * g4.y + b4.y;
  y.z = dx2 * rstd * g4.z + b4.z;
  y.w = dx3 * rstd * g4.w + b4.w;
  *(float4*)xp = y;
  float4 wg4 = *(const float4*)(Wg + lane * 4);
  float4 wd4 = *(const float4*)(Wd + lane * 4);
  float gs = (y.x * wg4.x + y.y * wg4.y) + (y.z * wg4.z + y.w * wg4.w);
  float dsv = (y.x * wd4.x + y.y * wd4.y) + (y.z * wd4.z + y.w * wd4.w);
  gs = wred_sum(gs);
  dsv = wred_sum(dsv);
  if (lane == 0) {
    float xg = gs + bg[0];
    float sig;
    if (xg >= 0.f) {
      sig = 1.f / (1.f + expf(-xg));
    } else {
      float e = expf(xg);
      sig = e / (1.f + e);
    }
    wbit[row] = (sig >= 0.4f) ? 1 : 0;
    dsc[row] = dsv + bd[0];
  }
}

// ---------------- sequential LRU writer: 1 wave per batch ----------------
// Derivations: fast/slow fill in slot order (used-flags monotone); slow
// eviction (argmax age, all-used, distinct write steps) == circular buffer.
// Fast eviction = argmin of per-slot demotion score, first-index ties.
__global__ __launch_bounds__(64) void writer_k(
    const int* __restrict__ wbit, const float* __restrict__ dsc,
    int* __restrict__ ftok, int* __restrict__ stok, int* __restrict__ cnt) {
  const int b = blockIdx.x;
  const int lane = threadIdx.x;
  __shared__ int stok_l[256];
  unsigned long long gm[16];
  float dv[16];
#pragma unroll
  for (int c = 0; c < 16; ++c) {
    int t = c * 64 + lane;
    int g = 0;
    float d = 0.f;
    if (t < 1021) {  // T-3 tokens
      g = wbit[b * 1024 + t];
      d = dsc[b * 1024 + t];
    }
    gm[c] = __ballot(g != 0);
    dv[c] = d;
  }
  int tok = -1;
  float mds = 0.f;  // this lane's fast-slot token and demotion score
  int wc = 0, dc = 0;
#pragma unroll
  for (int c = 0; c < 16; ++c) {
    unsigned long long m = gm[c];
    while (m) {
      int j = __ffsll(m) - 1;
      m &= m - 1;
      int t = c * 64 + j;
      float d = __shfl(dv[c], j);
      if (wc < 64) {
        if (lane == wc) { tok = t; mds = d; }
        ++wc;
      } else {
        float v = mds;
#pragma unroll
        for (int o = 32; o; o >>= 1) v = fminf(v, __shfl_xor(v, o));
        unsigned long long eq = __ballot(mds == v);
        int mi = __ffsll(eq) - 1;   // first index among minima (jnp.argmin)
        int dt = __shfl(tok, mi);   // demoted token
        if (lane == 0) stok_l[dc & 255] = dt;
        ++dc;
        if (lane == mi) { tok = t; mds = d; }
      }
    }
  }
  __syncthreads();
  ftok[b * 64 + lane] = tok;
#pragma unroll
  for (int i = 0; i < 4; ++i) stok[b * 256 + i * 64 + lane] = stok_l[i * 64 + lane];
  if (lane == 0) {
    cnt[b * 2] = wc;
    cnt[b * 2 + 1] = dc;
  }
}

// ---------------- q, dual attention, ctx, need_slow ----------------
__global__ __launch_bounds__(256) void attn_k(
    const float* __restrict__ X, const float* __restrict__ Wq,
    const float* __restrict__ bq, const int* __restrict__ ftok,
    const int* __restrict__ stok, const int* __restrict__ cnt,
    float* __restrict__ ctx, float* __restrict__ needs_out) {
  const int b = blockIdx.x;
  const int tid = threadIdx.x;
  const int lane = tid & 63, w = tid >> 6;
  __shared__ float hl[256], q[256];
  __shared__ float sc_f[64], at_f[64];
  __shared__ float sc_s[256], at_s[256];
  __shared__ int ft[64], st[256];
  __shared__ float red[8];
  __shared__ float needs_s;
  const float* Xb = X + (size_t)b * 1024 * 256;
  hl[tid] = Xb[(size_t)1023 * 256 + tid];
  if (tid < 64) ft[tid] = ftok[b * 64 + tid];
  st[tid] = stok[b * 256 + tid];
  __syncthreads();
  const int nf = min(cnt[b * 2], 64);
  const int ns = min(cnt[b * 2 + 1], 256);
  // q = h_last @ Wq + bq
  {
    float a = 0.f;
    for (int k = 0; k < 256; ++k) a = fmaf(hl[k], Wq[k * 256 + tid], a);
    q[tid] = a + bq[tid];
  }
  __syncthreads();
  // fast scores (4 waves x 16 slots)
  for (int i = w * 16; i < w * 16 + 16; ++i) {
    float sc = NEGV;
    if (i < nf) {
      const float4 xr = *(const float4*)(Xb + (size_t)ft[i] * 256 + lane * 4);
      const float4 qq = *(const float4*)(q + lane * 4);
      float p = (xr.x * qq.x + xr.y * qq.y) + (xr.z * qq.z + xr.w * qq.w);
      sc = wred_sum(p);
    }
    if (lane == 0) sc_f[i] = sc;
  }
  __syncthreads();
  if (w == 0) {
    float s = sc_f[lane];
    float mx = wred_max(s);
    float e = expf(s - mx);
    float sm = wred_sum(e);
    float a = e / sm;
    at_f[lane] = a;
    float ma = wred_max(a);
    if (lane == 0) needs_s = (ma < 0.3f) ? 1.f : 0.f;
  }
  __syncthreads();
  // slow scores (4 waves x 64 slots)
  for (int i = w * 64; i < w * 64 + 64; ++i) {
    float sc = NEGV;
    if (i < ns) {
      const float4 xr = *(const float4*)(Xb + (size_t)st[i] * 256 + lane * 4);
      const float4 qq = *(const float4*)(q + lane * 4);
      float p = (xr.x * qq.x + xr.y * qq.y) + (xr.z * qq.z + xr.w * qq.w);
      sc = wred_sum(p);
    }
    if (lane == 0) sc_s[i] = sc;
  }
  __syncthreads();
  // slow softmax over 256
  {
    float s = sc_s[tid];
    float mx = wred_max(s);
    if (lane == 0) red[w] = mx;
    __syncthreads();
    mx = fmaxf(fmaxf(red[0], red[1]), fmaxf(red[2], red[3]));
    float e = expf(s - mx);
    float sm = wred_sum(e);
    if (lane == 0) red[4 + w] = sm;
    __syncthreads();
    sm = (red[4] + red[5]) + (red[6] + red[7]);
    at_s[tid] = e / sm;
  }
  __syncthreads();
  float f = 0.f;
  for (int i = 0; i < nf; ++i)
    f = fmaf(at_f[i], Xb[(size_t)ft[i] * 256 + tid], f);
  float sx = 0.f;
  for (int i = 0; i < ns; ++i)
    sx = fmaf(at_s[i], Xb[(size_t)st[i] * 256 + tid], sx);
  float needs = needs_s;
  ctx[b * 256 + tid] = f + needs * sx;
  if (tid == 0) needs_out[b] = needs;
}

// ---------------- logits = ctx @ Wo + bo, all 32 batches per block ----------------
__global__ __launch_bounds__(256) void logits_k(
    const float* __restrict__ ctx, const float* __restrict__ Wo,
    const float* __restrict__ bo, float* __restrict__ out) {
  __shared__ float cs[256 * 36];  // transposed [h][b], pad 36 for alignment
  const int tid = threadIdx.x;
  for (int i = tid; i < 32 * 256; i += 256) {
    int bb = i >> 8, hh = i & 255;
    cs[hh * 36 + bb] = ctx[i];
  }
  __syncthreads();
  const int v = blockIdx.x * 256 + tid;
  float acc[32];
#pragma unroll
  for (int i = 0; i < 32; ++i) acc[i] = 0.f;
  for (int h = 0; h < 256; ++h) {
    float wv = Wo[(size_t)h * 32000 + v];
    const float4* cp = (const float4*)(cs + h * 36);
#pragma unroll
    for (int qq = 0; qq < 8; ++qq) {
      float4 c4 = cp[qq];
      acc[qq * 4 + 0] = fmaf(c4.x, wv, acc[qq * 4 + 0]);
      acc[qq * 4 + 1] = fmaf(c4.y, wv, acc[qq * 4 + 1]);
      acc[qq * 4 + 2] = fmaf(c4.z, wv, acc[qq * 4 + 2]);
      acc[qq * 4 + 3] = fmaf(c4.w, wv, acc[qq * 4 + 3]);
    }
  }
  float bv = bo[v];
#pragma unroll
  for (int bb = 0; bb < 32; ++bb) out[(size_t)bb * 32000 + v] = acc[bb] + bv;
}

extern "C" void kernel_launch(void* const* d_in, const int* in_sizes, int n_in,
                              void* d_out, int out_size, void* d_ws,
                              size_t ws_size, hipStream_t stream) {
  const int* seq = (const int*)d_in[0];
  const float* embed = (const float*)d_in[1];
  const float* W1 = (const float*)d_in[2];
  const float* b1 = (const float*)d_in[3];
  const float* W2 = (const float*)d_in[4];
  const float* b2 = (const float*)d_in[5];
  const float* gamma = (const float*)d_in[6];
  const float* beta = (const float*)d_in[7];
  const float* Wg = (const float*)d_in[8];
  const float* bg = (const float*)d_in[9];
  const float* Wd = (const float*)d_in[10];
  const float* bd = (const float*)d_in[11];
  const float* Wq = (const float*)d_in[12];
  const float* bq = (const float*)d_in[13];
  const float* Wo = (const float*)d_in[14];
  const float* bo = (const float*)d_in[15];
  float* out = (float*)d_out;

  char* wsb = (char*)d_ws;
  float* act1 = (float*)(wsb);                  // 8192*512*4   = 16 MiB (chunk)
  float* X = (float*)(wsb + 16777216);          // 32768*256*4  = 32 MiB
  int* wbit = (int*)(wsb + 50331648);           // 32768*4
  float* dscp = (float*)(wsb + 50462720);       // 32768*4
  int* ftokp = (int*)(wsb + 50593792);          // 32*64*4
  int* stokp = (int*)(wsb + 50601984);          // 32*256*4
  int* cntp = (int*)(wsb + 50634752);           // 32*2*4 (padded 256)
  float* ctxp = (float*)(wsb + 50635008);       // 32*256*4

  dim3 blk(256);
  // MLP in 4 row-chunks of 8192 to bound workspace (act1 reused per chunk)
  for (int c = 0; c < 4; ++c) {
    int row0 = c * 8192;
    dim3 g1(128, 4);  // 8192/64 x 512/128
    gemm_k<256, 512, true, true, false, 512>
        <<<g1, blk, 0, stream>>>(nullptr, W1, b1, embed, seq + row0, act1);
    dim3 g2(128, 2);  // 8192/64 x 256/128
    gemm_k<512, 256, false, false, true, 256>
        <<<g2, blk, 0, stream>>>(act1, W2, b2, embed, seq + row0,
                                 X + (size_t)row0 * 256);
  }
  ln_k<<<8192, blk, 0, stream>>>(X, gamma, beta, Wg, bg, Wd, bd, wbit, dscp);
  writer_k<<<32, dim3(64), 0, stream>>>(wbit, dscp, ftokp, stokp, cntp);
  attn_k<<<32, blk, 0, stream>>>(X, Wq, bq, ftokp, stokp, cntp, ctxp,
                                 out + (size_t)32 * 32000);
  logits_k<<<125, blk, 0, stream>>>(ctxp, Wo, bo, out);
}

// Round 2
// 597.491 us; speedup vs baseline: 1.2077x; 1.2077x over previous
//
#include <hip/hip_runtime.h>
#include <hip/hip_bf16.h>
#include <cstdint>

#define NEGV -1e9f

// ---------------- wave helpers (wave64) ----------------
__device__ __forceinline__ float wred_sum(float v) {
#pragma unroll
  for (int o = 32; o; o >>= 1) v += __shfl_xor(v, o);
  return v;
}
__device__ __forceinline__ float wred_max(float v) {
#pragma unroll
  for (int o = 32; o; o >>= 1) v = fmaxf(v, __shfl_xor(v, o));
  return v;
}

// DPP-based min fold step: VALU latency, no LDS pipe. old=self makes
// masked/invalid lanes contribute their own value (idempotent for min).
template <int CTRL>
__device__ __forceinline__ float dpp_fmin(float x) {
  int xi = __float_as_int(x);
  int yi = __builtin_amdgcn_update_dpp(xi, xi, CTRL, 0xF, 0xF, false);
  return fminf(x, __int_as_float(yi));
}

// ---------------- fused GEMM ----------------
// out[m,n] = epilogue( sum_k A[m,k]*B[k,n] + bias[n] )
// GEMM1: A = embed[seq[m]] (gather), RELU, out=act1 (stride 512)
// GEMM2: A = act1, +embed[seq[m]][n] residual, out=X (stride 256)
template <int KDIM, int BSTRIDE, bool GATHER_A, bool RELU_, bool ADD_EMBED, int OUTSTRIDE>
__global__ __launch_bounds__(256) void gemm_k(
    const float* __restrict__ Asrc, const float* __restrict__ Bsrc,
    const float* __restrict__ bias, const float* __restrict__ embed,
    const int* __restrict__ seq, float* __restrict__ out) {
  __shared__ float As[32][68];   // transposed A tile: As[k][m]
  __shared__ float Bs[32][132];
  __shared__ int sidx[64];
  const int tid = threadIdx.x;
  const int m0 = blockIdx.x * 64;
  const int n0 = blockIdx.y * 128;
  if (GATHER_A || ADD_EMBED) {
    if (tid < 64) sidx[tid] = seq[m0 + tid];
  }
  __syncthreads();

  const int ty = tid >> 4, tx = tid & 15;
  float acc[4][8];
#pragma unroll
  for (int i = 0; i < 4; ++i)
#pragma unroll
    for (int j = 0; j < 8; ++j) acc[i][j] = 0.f;

  for (int k0 = 0; k0 < KDIM; k0 += 32) {
    // stage A: 64 rows x 32 k (512 float4, 2/thread), transposed into LDS
#pragma unroll
    for (int j = 0; j < 2; ++j) {
      int f = tid + j * 256;
      int m = f >> 3, kq = f & 7;
      const float* ap;
      if constexpr (GATHER_A)
        ap = embed + (size_t)sidx[m] * 256 + k0 + kq * 4;
      else
        ap = Asrc + (size_t)(m0 + m) * KDIM + k0 + kq * 4;
      float4 a = *(const float4*)ap;
      As[kq * 4 + 0][m] = a.x;
      As[kq * 4 + 1][m] = a.y;
      As[kq * 4 + 2][m] = a.z;
      As[kq * 4 + 3][m] = a.w;
    }
    // stage B: 32 rows x 128 (1024 float4, 4/thread)
#pragma unroll
    for (int j = 0; j < 4; ++j) {
      int f = tid + j * 256;
      int r = f >> 5, cq = f & 31;
      *(float4*)&Bs[r][cq * 4] =
          *(const float4*)(Bsrc + (size_t)(k0 + r) * BSTRIDE + n0 + cq * 4);
    }
    __syncthreads();
#pragma unroll
    for (int kk = 0; kk < 32; ++kk) {
      float4 av = *(const float4*)&As[kk][ty * 4];
      float4 b0 = *(const float4*)&Bs[kk][tx * 8];
      float4 b1v = *(const float4*)&Bs[kk][tx * 8 + 4];
      float a_[4] = {av.x, av.y, av.z, av.w};
      float b_[8] = {b0.x, b0.y, b0.z, b0.w, b1v.x, b1v.y, b1v.z, b1v.w};
#pragma unroll
      for (int i = 0; i < 4; ++i)
#pragma unroll
        for (int j = 0; j < 8; ++j) acc[i][j] += a_[i] * b_[j];
    }
    __syncthreads();
  }

  float bs[8];
#pragma unroll
  for (int j = 0; j < 8; ++j) bs[j] = bias[n0 + tx * 8 + j];
#pragma unroll
  for (int i = 0; i < 4; ++i) {
    const int m = m0 + ty * 4 + i;
    float r[8];
#pragma unroll
    for (int j = 0; j < 8; ++j) {
      float t = acc[i][j] + bs[j];
      if constexpr (RELU_) t = fmaxf(t, 0.f);
      r[j] = t;
    }
    if constexpr (ADD_EMBED) {
      const float* ep = embed + (size_t)sidx[ty * 4 + i] * 256 + n0 + tx * 8;
      float4 e0 = *(const float4*)ep;
      float4 e1 = *(const float4*)(ep + 4);
      r[0] += e0.x; r[1] += e0.y; r[2] += e0.z; r[3] += e0.w;
      r[4] += e1.x; r[5] += e1.y; r[6] += e1.z; r[7] += e1.w;
    }
    float* op = out + (size_t)m * OUTSTRIDE + n0 + tx * 8;
    float4 v0 = {r[0], r[1], r[2], r[3]};
    float4 v1 = {r[4], r[5], r[6], r[7]};
    *(float4*)op = v0;
    *(float4*)(op + 4) = v1;
  }
}

// ---------------- LayerNorm (in place) + gate/demotion precompute ----------------
__global__ __launch_bounds__(256) void ln_k(
    float* __restrict__ X, const float* __restrict__ gamma,
    const float* __restrict__ beta, const float* __restrict__ Wg,
    const float* __restrict__ bg, const float* __restrict__ Wd,
    const float* __restrict__ bd, int* __restrict__ wbit,
    float* __restrict__ dsc) {
  const int row = blockIdx.x * 4 + (threadIdx.x >> 6);
  const int lane = threadIdx.x & 63;
  float* xp = X + (size_t)row * 256 + lane * 4;
  float4 x = *(float4*)xp;
  float s = (x.x + x.y) + (x.z + x.w);
  s = wred_sum(s);
  float mu = s * (1.f / 256.f);
  float dx0 = x.x - mu, dx1 = x.y - mu, dx2 = x.z - mu, dx3 = x.w - mu;
  float v = (dx0 * dx0 + dx1 * dx1) + (dx2 * dx2 + dx3 * dx3);
  v = wred_sum(v);
  float rstd = 1.f / sqrtf(v * (1.f / 256.f) + 1e-5f);
  float4 g4 = *(const float4*)(gamma + lane * 4);
  float4 b4 = *(const float4*)(beta + lane * 4);
  float4 y;
  y.x = dx0 * rstd * g4.x + b4.x;
  y.y = dx1 * rstd * g4.y + b4.y;
  y.z = dx2 * rstd * g4.z + b4.z;
  y.w = dx3 * rstd * g4.w + b4.w;
  *(float4*)xp = y;
  float4 wg4 = *(const float4*)(Wg + lane * 4);
  float4 wd4 = *(const float4*)(Wd + lane * 4);
  float gs = (y.x * wg4.x + y.y * wg4.y) + (y.z * wg4.z + y.w * wg4.w);
  float dsv = (y.x * wd4.x + y.y * wd4.y) + (y.z * wd4.z + y.w * wd4.w);
  gs = wred_sum(gs);
  dsv = wred_sum(dsv);
  if (lane == 0) {
    float xg = gs + bg[0];
    float sig;
    if (xg >= 0.f) {
      sig = 1.f / (1.f + expf(-xg));
    } else {
      float e = expf(xg);
      sig = e / (1.f + e);
    }
    wbit[row] = (sig >= 0.4f) ? 1 : 0;
    dsc[row] = dsv + bd[0];
  }
}

// ---------------- sequential LRU writer: 1 wave per batch ----------------
// Derivations: fast/slow fill in slot order (used-flags monotone); slow
// eviction (argmax age, all-used, distinct write steps) == circular buffer.
// Fast eviction = argmin of per-slot demotion score, first-index ties.
// Critical path per demotion is all-VALU: 6 DPP min levels + readlane +
// ballot + readlane (no LDS-pipe shuffles).
__global__ __launch_bounds__(64) void writer_k(
    const int* __restrict__ wbit, const float* __restrict__ dsc,
    int* __restrict__ ftok, int* __restrict__ stok, int* __restrict__ cnt) {
  const int b = blockIdx.x;
  const int lane = threadIdx.x;
  __shared__ int stok_l[256];
  int tok = -1;
  float mds = 0.f;  // this lane's fast-slot token and demotion score
  int wc = 0, dc = 0;
  for (int c = 0; c < 16; ++c) {
    const int t0 = c * 64;
    const int t = t0 + lane;
    int g = 0;
    float d = 0.f;
    if (t < 1021) {  // T-3 tokens
      g = wbit[b * 1024 + t];
      d = dsc[b * 1024 + t];
    }
    unsigned long long m = __ballot(g != 0);
    const int di = __float_as_int(d);
    while (m) {
      const int j = __ffsll(m) - 1;
      m &= m - 1;
      const float dj =
          __int_as_float(__builtin_amdgcn_readlane(di, j));  // off crit path
      if (wc < 64) {
        if (lane == wc) { tok = t0 + j; mds = dj; }
        ++wc;
      } else {
        float v = mds;
        v = dpp_fmin<0xB1>(v);   // quad_perm xor1
        v = dpp_fmin<0x4E>(v);   // quad_perm xor2
        v = dpp_fmin<0x141>(v);  // row_half_mirror (fold 4 -> 8)
        v = dpp_fmin<0x140>(v);  // row_mirror      (fold 8 -> 16)
        v = dpp_fmin<0x142>(v);  // row_bcast15     (fold rows 0|1, 2|3)
        v = dpp_fmin<0x143>(v);  // row_bcast31     (lane 63 = global min)
        const float vmin =
            __int_as_float(__builtin_amdgcn_readlane(__float_as_int(v), 63));
        const unsigned long long eq = __ballot(mds == vmin);
        const int mi = __ffsll(eq) - 1;  // first slot among minima (jnp.argmin)
        const int dt = __builtin_amdgcn_readlane(tok, mi);  // demoted token
        if (lane == 0) stok_l[dc & 255] = dt;
        ++dc;
        if (lane == mi) { tok = t0 + j; mds = dj; }
      }
    }
  }
  __syncthreads();
  ftok[b * 64 + lane] = tok;
#pragma unroll
  for (int i = 0; i < 4; ++i) stok[b * 256 + i * 64 + lane] = stok_l[i * 64 + lane];
  if (lane == 0) {
    cnt[b * 2] = wc;
    cnt[b * 2 + 1] = dc;
  }
}

// ---------------- q, dual attention, ctx, need_slow ----------------
__global__ __launch_bounds__(256) void attn_k(
    const float* __restrict__ X, const float* __restrict__ Wq,
    const float* __restrict__ bq, const int* __restrict__ ftok,
    const int* __restrict__ stok, const int* __restrict__ cnt,
    float* __restrict__ ctx, float* __restrict__ needs_out) {
  const int b = blockIdx.x;
  const int tid = threadIdx.x;
  const int lane = tid & 63, w = tid >> 6;
  __shared__ float hl[256], q[256];
  __shared__ float sc_f[64], at_f[64];
  __shared__ float sc_s[256], at_s[256];
  __shared__ int ft[64], st[256];
  __shared__ float red[8];
  __shared__ float needs_s;
  const float* Xb = X + (size_t)b * 1024 * 256;
  hl[tid] = Xb[(size_t)1023 * 256 + tid];
  if (tid < 64) ft[tid] = ftok[b * 64 + tid];
  st[tid] = stok[b * 256 + tid];
  __syncthreads();
  const int nf = min(cnt[b * 2], 64);
  const int ns = min(cnt[b * 2 + 1], 256);
  // q = h_last @ Wq + bq
  {
    float a = 0.f;
    for (int k = 0; k < 256; ++k) a = fmaf(hl[k], Wq[k * 256 + tid], a);
    q[tid] = a + bq[tid];
  }
  __syncthreads();
  // fast scores (4 waves x 16 slots)
  for (int i = w * 16; i < w * 16 + 16; ++i) {
    float sc = NEGV;
    if (i < nf) {
      const float4 xr = *(const float4*)(Xb + (size_t)ft[i] * 256 + lane * 4);
      const float4 qq = *(const float4*)(q + lane * 4);
      float p = (xr.x * qq.x + xr.y * qq.y) + (xr.z * qq.z + xr.w * qq.w);
      sc = wred_sum(p);
    }
    if (lane == 0) sc_f[i] = sc;
  }
  __syncthreads();
  if (w == 0) {
    float s = sc_f[lane];
    float mx = wred_max(s);
    float e = expf(s - mx);
    float sm = wred_sum(e);
    float a = e / sm;
    at_f[lane] = a;
    float ma = wred_max(a);
    if (lane == 0) needs_s = (ma < 0.3f) ? 1.f : 0.f;
  }
  __syncthreads();
  // slow scores (4 waves x 64 slots)
  for (int i = w * 64; i < w * 64 + 64; ++i) {
    float sc = NEGV;
    if (i < ns) {
      const float4 xr = *(const float4*)(Xb + (size_t)st[i] * 256 + lane * 4);
      const float4 qq = *(const float4*)(q + lane * 4);
      float p = (xr.x * qq.x + xr.y * qq.y) + (xr.z * qq.z + xr.w * qq.w);
      sc = wred_sum(p);
    }
    if (lane == 0) sc_s[i] = sc;
  }
  __syncthreads();
  // slow softmax over 256
  {
    float s = sc_s[tid];
    float mx = wred_max(s);
    if (lane == 0) red[w] = mx;
    __syncthreads();
    mx = fmaxf(fmaxf(red[0], red[1]), fmaxf(red[2], red[3]));
    float e = expf(s - mx);
    float sm = wred_sum(e);
    if (lane == 0) red[4 + w] = sm;
    __syncthreads();
    sm = (red[4] + red[5]) + (red[6] + red[7]);
    at_s[tid] = e / sm;
  }
  __syncthreads();
  float f = 0.f;
  for (int i = 0; i < nf; ++i)
    f = fmaf(at_f[i], Xb[(size_t)ft[i] * 256 + tid], f);
  float sx = 0.f;
  for (int i = 0; i < ns; ++i)
    sx = fmaf(at_s[i], Xb[(size_t)st[i] * 256 + tid], sx);
  float needs = needs_s;
  ctx[b * 256 + tid] = f + needs * sx;
  if (tid == 0) needs_out[b] = needs;
}

// ---------------- logits = ctx @ Wo + bo, all 32 batches per block ----------------
__global__ __launch_bounds__(256) void logits_k(
    const float* __restrict__ ctx, const float* __restrict__ Wo,
    const float* __restrict__ bo, float* __restrict__ out) {
  __shared__ float cs[256 * 36];  // transposed [h][b], pad 36 for alignment
  const int tid = threadIdx.x;
  for (int i = tid; i < 32 * 256; i += 256) {
    int bb = i >> 8, hh = i & 255;
    cs[hh * 36 + bb] = ctx[i];
  }
  __syncthreads();
  const int v = blockIdx.x * 256 + tid;
  float acc[32];
#pragma unroll
  for (int i = 0; i < 32; ++i) acc[i] = 0.f;
  for (int h = 0; h < 256; ++h) {
    float wv = Wo[(size_t)h * 32000 + v];
    const float4* cp = (const float4*)(cs + h * 36);
#pragma unroll
    for (int qq = 0; qq < 8; ++qq) {
      float4 c4 = cp[qq];
      acc[qq * 4 + 0] = fmaf(c4.x, wv, acc[qq * 4 + 0]);
      acc[qq * 4 + 1] = fmaf(c4.y, wv, acc[qq * 4 + 1]);
      acc[qq * 4 + 2] = fmaf(c4.z, wv, acc[qq * 4 + 2]);
      acc[qq * 4 + 3] = fmaf(c4.w, wv, acc[qq * 4 + 3]);
    }
  }
  float bv = bo[v];
#pragma unroll
  for (int bb = 0; bb < 32; ++bb) out[(size_t)bb * 32000 + v] = acc[bb] + bv;
}

extern "C" void kernel_launch(void* const* d_in, const int* in_sizes, int n_in,
                              void* d_out, int out_size, void* d_ws,
                              size_t ws_size, hipStream_t stream) {
  const int* seq = (const int*)d_in[0];
  const float* embed = (const float*)d_in[1];
  const float* W1 = (const float*)d_in[2];
  const float* b1 = (const float*)d_in[3];
  const float* W2 = (const float*)d_in[4];
  const float* b2 = (const float*)d_in[5];
  const float* gamma = (const float*)d_in[6];
  const float* beta = (const float*)d_in[7];
  const float* Wg = (const float*)d_in[8];
  const float* bg = (const float*)d_in[9];
  const float* Wd = (const float*)d_in[10];
  const float* bd = (const float*)d_in[11];
  const float* Wq = (const float*)d_in[12];
  const float* bq = (const float*)d_in[13];
  const float* Wo = (const float*)d_in[14];
  const float* bo = (const float*)d_in[15];
  float* out = (float*)d_out;

  char* wsb = (char*)d_ws;
  float* act1 = (float*)(wsb);                  // 8192*512*4   = 16 MiB (chunk)
  float* X = (float*)(wsb + 16777216);          // 32768*256*4  = 32 MiB
  int* wbit = (int*)(wsb + 50331648);           // 32768*4
  float* dscp = (float*)(wsb + 50462720);       // 32768*4
  int* ftokp = (int*)(wsb + 50593792);          // 32*64*4
  int* stokp = (int*)(wsb + 50601984);          // 32*256*4
  int* cntp = (int*)(wsb + 50634752);           // 32*2*4 (padded 256)
  float* ctxp = (float*)(wsb + 50635008);       // 32*256*4

  dim3 blk(256);
  // MLP in 4 row-chunks of 8192 to bound workspace (act1 reused per chunk)
  for (int c = 0; c < 4; ++c) {
    int row0 = c * 8192;
    dim3 g1(128, 4);  // 8192/64 x 512/128
    gemm_k<256, 512, true, true, false, 512>
        <<<g1, blk, 0, stream>>>(nullptr, W1, b1, embed, seq + row0, act1);
    dim3 g2(128, 2);  // 8192/64 x 256/128
    gemm_k<512, 256, false, false, true, 256>
        <<<g2, blk, 0, stream>>>(act1, W2, b2, embed, seq + row0,
                                 X + (size_t)row0 * 256);
  }
  ln_k<<<8192, blk, 0, stream>>>(X, gamma, beta, Wg, bg, Wd, bd, wbit, dscp);
  writer_k<<<32, dim3(64), 0, stream>>>(wbit, dscp, ftokp, stokp, cntp);
  attn_k<<<32, blk, 0, stream>>>(X, Wq, bq, ftokp, stokp, cntp, ctxp,
                                 out + (size_t)32 * 32000);
  logits_k<<<125, blk, 0, stream>>>(ctxp, Wo, bo, out);
}

// Round 3
// 464.961 us; speedup vs baseline: 1.5519x; 1.2850x over previous
//
#include <hip/hip_runtime.h>
#include <hip/hip_bf16.h>
#include <cstdint>

#define NEGV -1e9f

// ---------------- wave helpers (wave64) ----------------
__device__ __forceinline__ float wred_sum(float v) {
#pragma unroll
  for (int o = 32; o; o >>= 1) v += __shfl_xor(v, o);
  return v;
}
__device__ __forceinline__ float wred_max(float v) {
#pragma unroll
  for (int o = 32; o; o >>= 1) v = fmaxf(v, __shfl_xor(v, o));
  return v;
}

// ---------------- fused GEMM ----------------
// out[m,n] = epilogue( sum_k A[m,k]*B[k,n] + bias[n] )
// GEMM1: A = embed[seq[m]] (gather), RELU, out=act1 (stride 512)
// GEMM2: A = act1, +embed[seq[m]][n] residual, out=X (stride 256)
template <int KDIM, int BSTRIDE, bool GATHER_A, bool RELU_, bool ADD_EMBED, int OUTSTRIDE>
__global__ __launch_bounds__(256) void gemm_k(
    const float* __restrict__ Asrc, const float* __restrict__ Bsrc,
    const float* __restrict__ bias, const float* __restrict__ embed,
    const int* __restrict__ seq, float* __restrict__ out) {
  __shared__ float As[32][68];   // transposed A tile: As[k][m]
  __shared__ float Bs[32][132];
  __shared__ int sidx[64];
  const int tid = threadIdx.x;
  const int m0 = blockIdx.x * 64;
  const int n0 = blockIdx.y * 128;
  if (GATHER_A || ADD_EMBED) {
    if (tid < 64) sidx[tid] = seq[m0 + tid];
  }
  __syncthreads();

  const int ty = tid >> 4, tx = tid & 15;
  float acc[4][8];
#pragma unroll
  for (int i = 0; i < 4; ++i)
#pragma unroll
    for (int j = 0; j < 8; ++j) acc[i][j] = 0.f;

  for (int k0 = 0; k0 < KDIM; k0 += 32) {
    // stage A: 64 rows x 32 k (512 float4, 2/thread), transposed into LDS
#pragma unroll
    for (int j = 0; j < 2; ++j) {
      int f = tid + j * 256;
      int m = f >> 3, kq = f & 7;
      const float* ap;
      if constexpr (GATHER_A)
        ap = embed + (size_t)sidx[m] * 256 + k0 + kq * 4;
      else
        ap = Asrc + (size_t)(m0 + m) * KDIM + k0 + kq * 4;
      float4 a = *(const float4*)ap;
      As[kq * 4 + 0][m] = a.x;
      As[kq * 4 + 1][m] = a.y;
      As[kq * 4 + 2][m] = a.z;
      As[kq * 4 + 3][m] = a.w;
    }
    // stage B: 32 rows x 128 (1024 float4, 4/thread)
#pragma unroll
    for (int j = 0; j < 4; ++j) {
      int f = tid + j * 256;
      int r = f >> 5, cq = f & 31;
      *(float4*)&Bs[r][cq * 4] =
          *(const float4*)(Bsrc + (size_t)(k0 + r) * BSTRIDE + n0 + cq * 4);
    }
    __syncthreads();
#pragma unroll
    for (int kk = 0; kk < 32; ++kk) {
      float4 av = *(const float4*)&As[kk][ty * 4];
      float4 b0 = *(const float4*)&Bs[kk][tx * 8];
      float4 b1v = *(const float4*)&Bs[kk][tx * 8 + 4];
      float a_[4] = {av.x, av.y, av.z, av.w};
      float b_[8] = {b0.x, b0.y, b0.z, b0.w, b1v.x, b1v.y, b1v.z, b1v.w};
#pragma unroll
      for (int i = 0; i < 4; ++i)
#pragma unroll
        for (int j = 0; j < 8; ++j) acc[i][j] += a_[i] * b_[j];
    }
    __syncthreads();
  }

  float bs[8];
#pragma unroll
  for (int j = 0; j < 8; ++j) bs[j] = bias[n0 + tx * 8 + j];
#pragma unroll
  for (int i = 0; i < 4; ++i) {
    const int m = m0 + ty * 4 + i;
    float r[8];
#pragma unroll
    for (int j = 0; j < 8; ++j) {
      float t = acc[i][j] + bs[j];
      if constexpr (RELU_) t = fmaxf(t, 0.f);
      r[j] = t;
    }
    if constexpr (ADD_EMBED) {
      const float* ep = embed + (size_t)sidx[ty * 4 + i] * 256 + n0 + tx * 8;
      float4 e0 = *(const float4*)ep;
      float4 e1 = *(const float4*)(ep + 4);
      r[0] += e0.x; r[1] += e0.y; r[2] += e0.z; r[3] += e0.w;
      r[4] += e1.x; r[5] += e1.y; r[6] += e1.z; r[7] += e1.w;
    }
    float* op = out + (size_t)m * OUTSTRIDE + n0 + tx * 8;
    float4 v0 = {r[0], r[1], r[2], r[3]};
    float4 v1 = {r[4], r[5], r[6], r[7]};
    *(float4*)op = v0;
    *(float4*)(op + 4) = v1;
  }
}

// ---------------- LayerNorm (in place) + gate/demotion precompute ----------------
__global__ __launch_bounds__(256) void ln_k(
    float* __restrict__ X, const float* __restrict__ gamma,
    const float* __restrict__ beta, const float* __restrict__ Wg,
    const float* __restrict__ bg, const float* __restrict__ Wd,
    const float* __restrict__ bd, int* __restrict__ wbit,
    float* __restrict__ dsc) {
  const int row = blockIdx.x * 4 + (threadIdx.x >> 6);
  const int lane = threadIdx.x & 63;
  float* xp = X + (size_t)row * 256 + lane * 4;
  float4 x = *(float4*)xp;
  float s = (x.x + x.y) + (x.z + x.w);
  s = wred_sum(s);
  float mu = s * (1.f / 256.f);
  float dx0 = x.x - mu, dx1 = x.y - mu, dx2 = x.z - mu, dx3 = x.w - mu;
  float v = (dx0 * dx0 + dx1 * dx1) + (dx2 * dx2 + dx3 * dx3);
  v = wred_sum(v);
  float rstd = 1.f / sqrtf(v * (1.f / 256.f) + 1e-5f);
  float4 g4 = *(const float4*)(gamma + lane * 4);
  float4 b4 = *(const float4*)(beta + lane * 4);
  float4 y;
  y.x = dx0 * rstd * g4.x + b4.x;
  y.y = dx1 * rstd * g4.y + b4.y;
  y.z = dx2 * rstd * g4.z + b4.z;
  y.w = dx3 * rstd * g4.w + b4.w;
  *(float4*)xp = y;
  float4 wg4 = *(const float4*)(Wg + lane * 4);
  float4 wd4 = *(const float4*)(Wd + lane * 4);
  float gs = (y.x * wg4.x + y.y * wg4.y) + (y.z * wg4.z + y.w * wg4.w);
  float dsv = (y.x * wd4.x + y.y * wd4.y) + (y.z * wd4.z + y.w * wd4.w);
  gs = wred_sum(gs);
  dsv = wred_sum(dsv);
  if (lane == 0) {
    float xg = gs + bg[0];
    float sig;
    if (xg >= 0.f) {
      sig = 1.f / (1.f + expf(-xg));
    } else {
      float e = expf(xg);
      sig = e / (1.f + e);
    }
    wbit[row] = (sig >= 0.4f) ? 1 : 0;
    dsc[row] = dsv + bd[0];
  }
}

// ---------------- offline LRU selection (replaces sequential writer) ----------
// Replace-min process => evicted multiset after k demotions E_k = k smallest
// of A_{63+k} (first 63+k written scores). With W writes, K=W-64 demotions:
//   fast = last write + 63 largest of first W-1 writes
//   slow = E_K \ E_{K-256}; E_K = K smallest of A_{W-1},
//          E_{K-256} = (K-256) smallest of A_{W-257}
// Ties are equal token ids (h is a pure function of token id) -> any copy is
// value-equivalent; canonical (value,arrival) order makes the multiset
// difference a plain set difference. Slot order is irrelevant downstream
// (softmax/ctx are permutation-invariant sums over slots).
__global__ __launch_bounds__(1024) void select_k(
    const int* __restrict__ wbit, const float* __restrict__ dsc,
    int* __restrict__ ftok, int* __restrict__ stok, int* __restrict__ cnt) {
  const int b = blockIdx.x;
  const int tid = threadIdx.x;
  const int lane = tid & 63, wv = tid >> 6;  // 16 waves
  __shared__ unsigned long long skey[1024];
  __shared__ int stokl[1024];
  __shared__ int wavecnt[16];
  __shared__ int waveoff[17];
  __shared__ int fcnt_s[16], scnt_s[16];
  __shared__ int foff[16], soff[16];

  // 1) compact the write list (arrival order) via ballot prefix
  const int t = tid;
  int flag = 0;
  float d = 0.f;
  if (t < 1021) {  // T-3 tokens
    flag = wbit[b * 1024 + t];
    d = dsc[b * 1024 + t];
  }
  const unsigned long long m = __ballot(flag != 0);
  if (lane == 0) wavecnt[wv] = __popcll(m);
  __syncthreads();
  if (tid == 0) {
    int acc = 0;
    for (int i = 0; i < 16; ++i) { waveoff[i] = acc; acc += wavecnt[i]; }
    waveoff[16] = acc;
  }
  __syncthreads();
  const int W = waveoff[16];
  if (flag) {
    unsigned u = __float_as_uint(d);
    u = (u & 0x80000000u) ? ~u : (u | 0x80000000u);  // monotone float->uint
    const int w = waveoff[wv] + __popcll(m & ((1ull << lane) - 1ull));
    skey[w] = ((unsigned long long)u << 32) | (unsigned)w;
    stokl[w] = t;
  }
  __syncthreads();

  // 2) rank each write against the two prefixes
  const int K = W - 64;
  const int end2 = max(0, W - 257);   // j < end2 <=> arrival within first W-257
  const int endAll = W - 1;           // j < endAll <=> arrival within first W-1
  bool fastf = false, slowf = false;
  if (tid < W) {
    const unsigned long long ki = skey[tid];
    int r1 = 0, r2 = 0;
    int j = 0;
    for (; j < end2; ++j) {
      const int lt = skey[j] < ki;
      r1 += lt;
      r2 += lt;
    }
    for (; j < endAll; ++j) r1 += (skey[j] < ki);
    const bool isLast = (tid == W - 1);
    const bool inEK = (!isLast) && (r1 < K);
    const bool inE2 = (tid < end2) && (r2 < K - 256);
    fastf = isLast || (!isLast && r1 >= K);
    slowf = inEK && !inE2;
  }

  // 3) deterministic compaction (ballot prefix) to output slots
  const unsigned long long mf = __ballot(fastf);
  const unsigned long long ms = __ballot(slowf);
  if (lane == 0) { fcnt_s[wv] = __popcll(mf); scnt_s[wv] = __popcll(ms); }
  __syncthreads();
  if (tid == 0) {
    int a = 0, c = 0;
    for (int i = 0; i < 16; ++i) {
      foff[i] = a; a += fcnt_s[i];
      soff[i] = c; c += scnt_s[i];
    }
  }
  __syncthreads();
  if (fastf) {
    const int p = foff[wv] + __popcll(mf & ((1ull << lane) - 1ull));
    ftok[b * 64 + p] = stokl[tid];
  }
  if (slowf) {
    const int p = soff[wv] + __popcll(ms & ((1ull << lane) - 1ull));
    stok[b * 256 + p] = stokl[tid];
  }
  if (tid == 0) {
    cnt[b * 2] = W;
    cnt[b * 2 + 1] = max(K, 0);
  }
}

// ---------------- q, dual attention, ctx, need_slow ----------------
__global__ __launch_bounds__(256) void attn_k(
    const float* __restrict__ X, const float* __restrict__ Wq,
    const float* __restrict__ bq, const int* __restrict__ ftok,
    const int* __restrict__ stok, const int* __restrict__ cnt,
    float* __restrict__ ctx, float* __restrict__ needs_out) {
  const int b = blockIdx.x;
  const int tid = threadIdx.x;
  const int lane = tid & 63, w = tid >> 6;
  __shared__ float hl[256], q[256];
  __shared__ float sc_f[64], at_f[64];
  __shared__ float sc_s[256], at_s[256];
  __shared__ int ft[64], st[256];
  __shared__ float red[8];
  __shared__ float needs_s;
  const float* Xb = X + (size_t)b * 1024 * 256;
  hl[tid] = Xb[(size_t)1023 * 256 + tid];
  if (tid < 64) ft[tid] = ftok[b * 64 + tid];
  st[tid] = stok[b * 256 + tid];
  __syncthreads();
  const int nf = min(cnt[b * 2], 64);
  const int ns = min(cnt[b * 2 + 1], 256);
  // q = h_last @ Wq + bq
  {
    float a = 0.f;
    for (int k = 0; k < 256; ++k) a = fmaf(hl[k], Wq[k * 256 + tid], a);
    q[tid] = a + bq[tid];
  }
  __syncthreads();
  // fast scores (4 waves x 16 slots)
  for (int i = w * 16; i < w * 16 + 16; ++i) {
    float sc = NEGV;
    if (i < nf) {
      const float4 xr = *(const float4*)(Xb + (size_t)ft[i] * 256 + lane * 4);
      const float4 qq = *(const float4*)(q + lane * 4);
      float p = (xr.x * qq.x + xr.y * qq.y) + (xr.z * qq.z + xr.w * qq.w);
      sc = wred_sum(p);
    }
    if (lane == 0) sc_f[i] = sc;
  }
  __syncthreads();
  if (w == 0) {
    float s = sc_f[lane];
    float mx = wred_max(s);
    float e = expf(s - mx);
    float sm = wred_sum(e);
    float a = e / sm;
    at_f[lane] = a;
    float ma = wred_max(a);
    if (lane == 0) needs_s = (ma < 0.3f) ? 1.f : 0.f;
  }
  __syncthreads();
  // slow scores (4 waves x 64 slots)
  for (int i = w * 64; i < w * 64 + 64; ++i) {
    float sc = NEGV;
    if (i < ns) {
      const float4 xr = *(const float4*)(Xb + (size_t)st[i] * 256 + lane * 4);
      const float4 qq = *(const float4*)(q + lane * 4);
      float p = (xr.x * qq.x + xr.y * qq.y) + (xr.z * qq.z + xr.w * qq.w);
      sc = wred_sum(p);
    }
    if (lane == 0) sc_s[i] = sc;
  }
  __syncthreads();
  // slow softmax over 256
  {
    float s = sc_s[tid];
    float mx = wred_max(s);
    if (lane == 0) red[w] = mx;
    __syncthreads();
    mx = fmaxf(fmaxf(red[0], red[1]), fmaxf(red[2], red[3]));
    float e = expf(s - mx);
    float sm = wred_sum(e);
    if (lane == 0) red[4 + w] = sm;
    __syncthreads();
    sm = (red[4] + red[5]) + (red[6] + red[7]);
    at_s[tid] = e / sm;
  }
  __syncthreads();
  float f = 0.f;
  for (int i = 0; i < nf; ++i)
    f = fmaf(at_f[i], Xb[(size_t)ft[i] * 256 + tid], f);
  float sx = 0.f;
  for (int i = 0; i < ns; ++i)
    sx = fmaf(at_s[i], Xb[(size_t)st[i] * 256 + tid], sx);
  float needs = needs_s;
  ctx[b * 256 + tid] = f + needs * sx;
  if (tid == 0) needs_out[b] = needs;
}

// ---------------- logits = ctx @ Wo + bo, all 32 batches per block ----------------
__global__ __launch_bounds__(256) void logits_k(
    const float* __restrict__ ctx, const float* __restrict__ Wo,
    const float* __restrict__ bo, float* __restrict__ out) {
  __shared__ float cs[256 * 36];  // transposed [h][b], pad 36 for alignment
  const int tid = threadIdx.x;
  for (int i = tid; i < 32 * 256; i += 256) {
    int bb = i >> 8, hh = i & 255;
    cs[hh * 36 + bb] = ctx[i];
  }
  __syncthreads();
  const int v = blockIdx.x * 256 + tid;
  float acc[32];
#pragma unroll
  for (int i = 0; i < 32; ++i) acc[i] = 0.f;
  for (int h = 0; h < 256; ++h) {
    float wv = Wo[(size_t)h * 32000 + v];
    const float4* cp = (const float4*)(cs + h * 36);
#pragma unroll
    for (int qq = 0; qq < 8; ++qq) {
      float4 c4 = cp[qq];
      acc[qq * 4 + 0] = fmaf(c4.x, wv, acc[qq * 4 + 0]);
      acc[qq * 4 + 1] = fmaf(c4.y, wv, acc[qq * 4 + 1]);
      acc[qq * 4 + 2] = fmaf(c4.z, wv, acc[qq * 4 + 2]);
      acc[qq * 4 + 3] = fmaf(c4.w, wv, acc[qq * 4 + 3]);
    }
  }
  float bv = bo[v];
#pragma unroll
  for (int bb = 0; bb < 32; ++bb) out[(size_t)bb * 32000 + v] = acc[bb] + bv;
}

extern "C" void kernel_launch(void* const* d_in, const int* in_sizes, int n_in,
                              void* d_out, int out_size, void* d_ws,
                              size_t ws_size, hipStream_t stream) {
  const int* seq = (const int*)d_in[0];
  const float* embed = (const float*)d_in[1];
  const float* W1 = (const float*)d_in[2];
  const float* b1 = (const float*)d_in[3];
  const float* W2 = (const float*)d_in[4];
  const float* b2 = (const float*)d_in[5];
  const float* gamma = (const float*)d_in[6];
  const float* beta = (const float*)d_in[7];
  const float* Wg = (const float*)d_in[8];
  const float* bg = (const float*)d_in[9];
  const float* Wd = (const float*)d_in[10];
  const float* bd = (const float*)d_in[11];
  const float* Wq = (const float*)d_in[12];
  const float* bq = (const float*)d_in[13];
  const float* Wo = (const float*)d_in[14];
  const float* bo = (const float*)d_in[15];
  float* out = (float*)d_out;

  char* wsb = (char*)d_ws;
  float* act1 = (float*)(wsb);                  // 8192*512*4   = 16 MiB (chunk)
  float* X = (float*)(wsb + 16777216);          // 32768*256*4  = 32 MiB
  int* wbit = (int*)(wsb + 50331648);           // 32768*4
  float* dscp = (float*)(wsb + 50462720);       // 32768*4
  int* ftokp = (int*)(wsb + 50593792);          // 32*64*4
  int* stokp = (int*)(wsb + 50601984);          // 32*256*4
  int* cntp = (int*)(wsb + 50634752);           // 32*2*4 (padded 256)
  float* ctxp = (float*)(wsb + 50635008);       // 32*256*4

  dim3 blk(256);
  // MLP in 4 row-chunks of 8192 to bound workspace (act1 reused per chunk)
  for (int c = 0; c < 4; ++c) {
    int row0 = c * 8192;
    dim3 g1(128, 4);  // 8192/64 x 512/128
    gemm_k<256, 512, true, true, false, 512>
        <<<g1, blk, 0, stream>>>(nullptr, W1, b1, embed, seq + row0, act1);
    dim3 g2(128, 2);  // 8192/64 x 256/128
    gemm_k<512, 256, false, false, true, 256>
        <<<g2, blk, 0, stream>>>(act1, W2, b2, embed, seq + row0,
                                 X + (size_t)row0 * 256);
  }
  ln_k<<<8192, blk, 0, stream>>>(X, gamma, beta, Wg, bg, Wd, bd, wbit, dscp);
  select_k<<<32, dim3(1024), 0, stream>>>(wbit, dscp, ftokp, stokp, cntp);
  attn_k<<<32, blk, 0, stream>>>(X, Wq, bq, ftokp, stokp, cntp, ctxp,
                                 out + (size_t)32 * 32000);
  logits_k<<<125, blk, 0, stream>>>(ctxp, Wo, bo, out);
}

// Round 4
// 329.381 us; speedup vs baseline: 2.1907x; 1.4116x over previous
//
#include <hip/hip_runtime.h>
#include <hip/hip_bf16.h>
#include <cstdint>

#define NEGV -1e9f

// ---------------- wave helpers (wave64) ----------------
__device__ __forceinline__ float wred_sum(float v) {
#pragma unroll
  for (int o = 32; o; o >>= 1) v += __shfl_xor(v, o);
  return v;
}
__device__ __forceinline__ float wred_max(float v) {
#pragma unroll
  for (int o = 32; o; o >>= 1) v = fmaxf(v, __shfl_xor(v, o));
  return v;
}

// DPP fold steps (VALU latency, no LDS pipe). old=self on non-target lanes;
// result valid in lane 63 after the full 6-step chain.
template <int CTRL>
__device__ __forceinline__ float dpp_fadd(float x) {
  int xi = __float_as_int(x);
  int yi = __builtin_amdgcn_update_dpp(xi, xi, CTRL, 0xF, 0xF, false);
  return x + __int_as_float(yi);
}
__device__ __forceinline__ float dpp_sum63(float v) {
  v = dpp_fadd<0xB1>(v);   // quad_perm xor1
  v = dpp_fadd<0x4E>(v);   // quad_perm xor2
  v = dpp_fadd<0x141>(v);  // row_half_mirror (4 -> 8)
  v = dpp_fadd<0x140>(v);  // row_mirror      (8 -> 16)
  v = dpp_fadd<0x142>(v);  // row_bcast15     (rows pairwise)
  v = dpp_fadd<0x143>(v);  // row_bcast31     (lane 63 = total)
  return v;                // only lane 63 holds the full sum
}

// ---------------- fused GEMM ----------------
// out[m,n] = epilogue( sum_k A[m,k]*B[k,n] + bias[n] )
// GEMM1: A = embed[seq[m]] (gather), RELU, out=act1 (stride 512)
// GEMM2: A = act1, +embed[seq[m]][n] residual, out=X (stride 256)
// NOTE: per-output fma order is k-ascending -> values bit-stable across
// grid/chunking changes (decision path depends on exact h).
template <int KDIM, int BSTRIDE, bool GATHER_A, bool RELU_, bool ADD_EMBED, int OUTSTRIDE>
__global__ __launch_bounds__(256) void gemm_k(
    const float* __restrict__ Asrc, const float* __restrict__ Bsrc,
    const float* __restrict__ bias, const float* __restrict__ embed,
    const int* __restrict__ seq, float* __restrict__ out) {
  __shared__ float As[32][68];   // transposed A tile: As[k][m]
  __shared__ float Bs[32][132];
  __shared__ int sidx[64];
  const int tid = threadIdx.x;
  const int m0 = blockIdx.x * 64;
  const int n0 = blockIdx.y * 128;
  if (GATHER_A || ADD_EMBED) {
    if (tid < 64) sidx[tid] = seq[m0 + tid];
  }
  __syncthreads();

  const int ty = tid >> 4, tx = tid & 15;
  float acc[4][8];
#pragma unroll
  for (int i = 0; i < 4; ++i)
#pragma unroll
    for (int j = 0; j < 8; ++j) acc[i][j] = 0.f;

  for (int k0 = 0; k0 < KDIM; k0 += 32) {
#pragma unroll
    for (int j = 0; j < 2; ++j) {
      int f = tid + j * 256;
      int m = f >> 3, kq = f & 7;
      const float* ap;
      if constexpr (GATHER_A)
        ap = embed + (size_t)sidx[m] * 256 + k0 + kq * 4;
      else
        ap = Asrc + (size_t)(m0 + m) * KDIM + k0 + kq * 4;
      float4 a = *(const float4*)ap;
      As[kq * 4 + 0][m] = a.x;
      As[kq * 4 + 1][m] = a.y;
      As[kq * 4 + 2][m] = a.z;
      As[kq * 4 + 3][m] = a.w;
    }
#pragma unroll
    for (int j = 0; j < 4; ++j) {
      int f = tid + j * 256;
      int r = f >> 5, cq = f & 31;
      *(float4*)&Bs[r][cq * 4] =
          *(const float4*)(Bsrc + (size_t)(k0 + r) * BSTRIDE + n0 + cq * 4);
    }
    __syncthreads();
#pragma unroll
    for (int kk = 0; kk < 32; ++kk) {
      float4 av = *(const float4*)&As[kk][ty * 4];
      float4 b0 = *(const float4*)&Bs[kk][tx * 8];
      float4 b1v = *(const float4*)&Bs[kk][tx * 8 + 4];
      float a_[4] = {av.x, av.y, av.z, av.w};
      float b_[8] = {b0.x, b0.y, b0.z, b0.w, b1v.x, b1v.y, b1v.z, b1v.w};
#pragma unroll
      for (int i = 0; i < 4; ++i)
#pragma unroll
        for (int j = 0; j < 8; ++j) acc[i][j] += a_[i] * b_[j];
    }
    __syncthreads();
  }

  float bs[8];
#pragma unroll
  for (int j = 0; j < 8; ++j) bs[j] = bias[n0 + tx * 8 + j];
#pragma unroll
  for (int i = 0; i < 4; ++i) {
    const int m = m0 + ty * 4 + i;
    float r[8];
#pragma unroll
    for (int j = 0; j < 8; ++j) {
      float t = acc[i][j] + bs[j];
      if constexpr (RELU_) t = fmaxf(t, 0.f);
      r[j] = t;
    }
    if constexpr (ADD_EMBED) {
      const float* ep = embed + (size_t)sidx[ty * 4 + i] * 256 + n0 + tx * 8;
      float4 e0 = *(const float4*)ep;
      float4 e1 = *(const float4*)(ep + 4);
      r[0] += e0.x; r[1] += e0.y; r[2] += e0.z; r[3] += e0.w;
      r[4] += e1.x; r[5] += e1.y; r[6] += e1.z; r[7] += e1.w;
    }
    float* op = out + (size_t)m * OUTSTRIDE + n0 + tx * 8;
    float4 v0 = {r[0], r[1], r[2], r[3]};
    float4 v1 = {r[4], r[5], r[6], r[7]};
    *(float4*)op = v0;
    *(float4*)(op + 4) = v1;
  }
}

// ---------------- LayerNorm (in place) + gate/demotion precompute ----------------
__global__ __launch_bounds__(256) void ln_k(
    float* __restrict__ X, const float* __restrict__ gamma,
    const float* __restrict__ beta, const float* __restrict__ Wg,
    const float* __restrict__ bg, const float* __restrict__ Wd,
    const float* __restrict__ bd, int* __restrict__ wbit,
    float* __restrict__ dsc) {
  const int row = blockIdx.x * 4 + (threadIdx.x >> 6);
  const int lane = threadIdx.x & 63;
  float* xp = X + (size_t)row * 256 + lane * 4;
  float4 x = *(float4*)xp;
  float s = (x.x + x.y) + (x.z + x.w);
  s = wred_sum(s);
  float mu = s * (1.f / 256.f);
  float dx0 = x.x - mu, dx1 = x.y - mu, dx2 = x.z - mu, dx3 = x.w - mu;
  float v = (dx0 * dx0 + dx1 * dx1) + (dx2 * dx2 + dx3 * dx3);
  v = wred_sum(v);
  float rstd = 1.f / sqrtf(v * (1.f / 256.f) + 1e-5f);
  float4 g4 = *(const float4*)(gamma + lane * 4);
  float4 b4 = *(const float4*)(beta + lane * 4);
  float4 y;
  y.x = dx0 * rstd * g4.x + b4.x;
  y.y = dx1 * rstd * g4.y + b4.y;
  y.z = dx2 * rstd * g4.z + b4.z;
  y.w = dx3 * rstd * g4.w + b4.w;
  *(float4*)xp = y;
  float4 wg4 = *(const float4*)(Wg + lane * 4);
  float4 wd4 = *(const float4*)(Wd + lane * 4);
  float gs = (y.x * wg4.x + y.y * wg4.y) + (y.z * wg4.z + y.w * wg4.w);
  float dsv = (y.x * wd4.x + y.y * wd4.y) + (y.z * wd4.z + y.w * wd4.w);
  gs = wred_sum(gs);
  dsv = wred_sum(dsv);
  if (lane == 0) {
    float xg = gs + bg[0];
    float sig;
    if (xg >= 0.f) {
      sig = 1.f / (1.f + expf(-xg));
    } else {
      float e = expf(xg);
      sig = e / (1.f + e);
    }
    wbit[row] = (sig >= 0.4f) ? 1 : 0;
    dsc[row] = dsv + bd[0];
  }
}

// ---------------- offline LRU selection (replaces sequential writer) ----------
// E_k (evicted multiset after k demotions) = k smallest of first 63+k writes.
// fast = last write + 63 largest of first W-1; slow = E_K \ E_{K-256}.
__global__ __launch_bounds__(1024) void select_k(
    const int* __restrict__ wbit, const float* __restrict__ dsc,
    int* __restrict__ ftok, int* __restrict__ stok, int* __restrict__ cnt) {
  const int b = blockIdx.x;
  const int tid = threadIdx.x;
  const int lane = tid & 63, wv = tid >> 6;  // 16 waves
  __shared__ unsigned long long skey[1024];
  __shared__ int stokl[1024];
  __shared__ int wavecnt[16];
  __shared__ int waveoff[17];
  __shared__ int fcnt_s[16], scnt_s[16];
  __shared__ int foff[16], soff[16];

  const int t = tid;
  int flag = 0;
  float d = 0.f;
  if (t < 1021) {
    flag = wbit[b * 1024 + t];
    d = dsc[b * 1024 + t];
  }
  const unsigned long long m = __ballot(flag != 0);
  if (lane == 0) wavecnt[wv] = __popcll(m);
  __syncthreads();
  if (tid == 0) {
    int acc = 0;
    for (int i = 0; i < 16; ++i) { waveoff[i] = acc; acc += wavecnt[i]; }
    waveoff[16] = acc;
  }
  __syncthreads();
  const int W = waveoff[16];
  if (flag) {
    unsigned u = __float_as_uint(d);
    u = (u & 0x80000000u) ? ~u : (u | 0x80000000u);
    const int w = waveoff[wv] + __popcll(m & ((1ull << lane) - 1ull));
    skey[w] = ((unsigned long long)u << 32) | (unsigned)w;
    stokl[w] = t;
  }
  __syncthreads();

  const int K = W - 64;
  const int end2 = max(0, W - 257);
  const int endAll = W - 1;
  bool fastf = false, slowf = false;
  if (tid < W) {
    const unsigned long long ki = skey[tid];
    int r1 = 0, r2 = 0;
    int j = 0;
    for (; j < end2; ++j) {
      const int lt = skey[j] < ki;
      r1 += lt;
      r2 += lt;
    }
    for (; j < endAll; ++j) r1 += (skey[j] < ki);
    const bool isLast = (tid == W - 1);
    const bool inEK = (!isLast) && (r1 < K);
    const bool inE2 = (tid < end2) && (r2 < K - 256);
    fastf = isLast || (!isLast && r1 >= K);
    slowf = inEK && !inE2;
  }

  const unsigned long long mf = __ballot(fastf);
  const unsigned long long ms = __ballot(slowf);
  if (lane == 0) { fcnt_s[wv] = __popcll(mf); scnt_s[wv] = __popcll(ms); }
  __syncthreads();
  if (tid == 0) {
    int a = 0, c = 0;
    for (int i = 0; i < 16; ++i) {
      foff[i] = a; a += fcnt_s[i];
      soff[i] = c; c += scnt_s[i];
    }
  }
  __syncthreads();
  if (fastf) {
    const int p = foff[wv] + __popcll(mf & ((1ull << lane) - 1ull));
    ftok[b * 64 + p] = stokl[tid];
  }
  if (slowf) {
    const int p = soff[wv] + __popcll(ms & ((1ull << lane) - 1ull));
    stok[b * 256 + p] = stokl[tid];
  }
  if (tid == 0) {
    cnt[b * 2] = W;
    cnt[b * 2 + 1] = max(K, 0);
  }
}

// ---------------- fused q + dual attention + ctx + need_slow, 16 waves ----
__global__ __launch_bounds__(1024) void attn2_k(
    const float* __restrict__ X, const float* __restrict__ Wq,
    const float* __restrict__ bq, const int* __restrict__ ftok,
    const int* __restrict__ stok, const int* __restrict__ cnt,
    float* __restrict__ ctx, float* __restrict__ needs_out) {
  const int b = blockIdx.x;
  const int tid = threadIdx.x;
  const int lane = tid & 63, wv = tid >> 6;  // 16 waves
  __shared__ float hl[256], q[256];
  __shared__ float qpart[4][256];
  __shared__ float sc_f[64], at_f[64];
  __shared__ float sc_s[256], at_s[256];
  __shared__ int ft[64], st[256];
  __shared__ float redm[4], reds[4];
  __shared__ float needs_s;
  __shared__ float cpart[16][256];
  const float* Xb = X + (size_t)b * 1024 * 256;
  if (tid < 256) hl[tid] = Xb[(size_t)1023 * 256 + tid];
  else if (tid < 320) ft[tid - 256] = ftok[b * 64 + tid - 256];
  else if (tid < 576) st[tid - 320] = stok[b * 256 + tid - 320];
  __syncthreads();
  const int nf = min(cnt[b * 2], 64);
  const int ns = min(cnt[b * 2 + 1], 256);

  // q = h_last @ Wq + bq, 4-way k-split
  {
    const int col = tid & 255, kc = tid >> 8;
    float a = 0.f;
    const float* wp = Wq + (size_t)(kc * 64) * 256 + col;
#pragma unroll 4
    for (int k = 0; k < 64; ++k) a = fmaf(hl[kc * 64 + k], wp[(size_t)k * 256], a);
    qpart[kc][col] = a;
  }
  __syncthreads();
  if (tid < 256)
    q[tid] = ((qpart[0][tid] + qpart[1][tid]) + qpart[2][tid]) + qpart[3][tid] +
             bq[tid];
  __syncthreads();

  // scores: 320 rows over 16 waves (r = wv + 16*i), DPP dot-reduce
  const float4 qq = *(const float4*)(q + lane * 4);
#pragma unroll 2
  for (int i = 0; i < 20; ++i) {
    const int r = wv + 16 * i;
    bool valid;
    int tok;
    if (r < 64) { valid = r < nf; tok = valid ? ft[r] : 0; }
    else        { valid = (r - 64) < ns; tok = valid ? st[r - 64] : 0; }
    float sc = NEGV;
    if (valid) {
      const float4 xr = *(const float4*)(Xb + (size_t)tok * 256 + lane * 4);
      float p = (xr.x * qq.x + xr.y * qq.y) + (xr.z * qq.z + xr.w * qq.w);
      sc = dpp_sum63(p);
    }
    if (lane == 63) {
      if (r < 64) sc_f[r] = sc;
      else sc_s[r - 64] = sc;
    }
  }
  __syncthreads();

  // fast softmax (wave 8) || slow max partials (waves 0-3)
  if (wv < 4) {
    float s = sc_s[tid];
    float mx = wred_max(s);
    if (lane == 0) redm[wv] = mx;
  } else if (wv == 8) {
    float s = sc_f[lane];
    float mx = wred_max(s);
    float e = expf(s - mx);
    float sm = wred_sum(e);
    float a = e / sm;
    at_f[lane] = a;
    float ma = wred_max(a);
    if (lane == 0) needs_s = (ma < 0.3f) ? 1.f : 0.f;
  }
  __syncthreads();
  if (wv < 4) {
    float s = sc_s[tid];
    float mx = fmaxf(fmaxf(redm[0], redm[1]), fmaxf(redm[2], redm[3]));
    float e = expf(s - mx);
    float sm = wred_sum(e);
    if (lane == 0) reds[wv] = sm;
    at_s[tid] = e;  // stash numerator
  }
  __syncthreads();
  if (tid < 256) {
    float sm = (reds[0] + reds[1]) + (reds[2] + reds[3]);
    at_s[tid] = at_s[tid] / sm;
  }
  __syncthreads();

  // ctx: wave partials over the same 20 rows, then LDS tree reduce
  const float needs = needs_s;
  float4 cp = {0.f, 0.f, 0.f, 0.f};
#pragma unroll 2
  for (int i = 0; i < 20; ++i) {
    const int r = wv + 16 * i;
    bool valid;
    int tok;
    float a;
    if (r < 64) { valid = r < nf; tok = valid ? ft[r] : 0; a = at_f[r]; }
    else {
      valid = (r - 64) < ns;
      tok = valid ? st[r - 64] : 0;
      a = needs * at_s[r - 64];
    }
    if (valid) {
      const float4 xr = *(const float4*)(Xb + (size_t)tok * 256 + lane * 4);
      cp.x = fmaf(a, xr.x, cp.x);
      cp.y = fmaf(a, xr.y, cp.y);
      cp.z = fmaf(a, xr.z, cp.z);
      cp.w = fmaf(a, xr.w, cp.w);
    }
  }
  *(float4*)&cpart[wv][lane * 4] = cp;
  __syncthreads();
  if (tid < 256) {
    float c = 0.f;
#pragma unroll
    for (int w = 0; w < 16; ++w) c += cpart[w][tid];
    ctx[b * 256 + tid] = c;
  }
  if (tid == 0) needs_out[b] = needs;
}

// ---------------- logits = ctx @ Wo + bo, batch-split grid (125,4) ----------
__global__ __launch_bounds__(256) void logits2_k(
    const float* __restrict__ ctx, const float* __restrict__ Wo,
    const float* __restrict__ bo, float* __restrict__ out) {
  __shared__ float cs[256 * 8];  // [h][bb]
  const int tid = threadIdx.x;
  const int b0 = blockIdx.y * 8;
  for (int i = tid; i < 2048; i += 256) {
    int bb = i & 7, hh = i >> 3;
    cs[hh * 8 + bb] = ctx[(b0 + bb) * 256 + hh];
  }
  __syncthreads();
  const int v = blockIdx.x * 256 + tid;
  float acc[8] = {0.f, 0.f, 0.f, 0.f, 0.f, 0.f, 0.f, 0.f};
#pragma unroll 4
  for (int h = 0; h < 256; ++h) {
    float wv = Wo[(size_t)h * 32000 + v];
#pragma unroll
    for (int bb = 0; bb < 8; ++bb) acc[bb] = fmaf(cs[h * 8 + bb], wv, acc[bb]);
  }
  float bv = bo[v];
#pragma unroll
  for (int bb = 0; bb < 8; ++bb)
    out[(size_t)(b0 + bb) * 32000 + v] = acc[bb] + bv;
}

extern "C" void kernel_launch(void* const* d_in, const int* in_sizes, int n_in,
                              void* d_out, int out_size, void* d_ws,
                              size_t ws_size, hipStream_t stream) {
  const int* seq = (const int*)d_in[0];
  const float* embed = (const float*)d_in[1];
  const float* W1 = (const float*)d_in[2];
  const float* b1 = (const float*)d_in[3];
  const float* W2 = (const float*)d_in[4];
  const float* b2 = (const float*)d_in[5];
  const float* gamma = (const float*)d_in[6];
  const float* beta = (const float*)d_in[7];
  const float* Wg = (const float*)d_in[8];
  const float* bg = (const float*)d_in[9];
  const float* Wd = (const float*)d_in[10];
  const float* bd = (const float*)d_in[11];
  const float* Wq = (const float*)d_in[12];
  const float* bq = (const float*)d_in[13];
  const float* Wo = (const float*)d_in[14];
  const float* bo = (const float*)d_in[15];
  float* out = (float*)d_out;

  char* wsb = (char*)d_ws;
  dim3 blk(256);
  const bool big = ws_size >= (size_t)101000000;

  float* X;
  int* wbit;
  float* dscp;
  int* ftokp;
  int* stokp;
  int* cntp;
  float* ctxp;

  if (big) {
    // single-dispatch GEMMs: act1 full 64 MiB, X 32 MiB
    float* act1 = (float*)(wsb);
    X = (float*)(wsb + 67108864);
    wbit = (int*)(wsb + 100663296);
    dscp = (float*)(wsb + 100794368);
    ftokp = (int*)(wsb + 100925440);
    stokp = (int*)(wsb + 100933632);
    cntp = (int*)(wsb + 100966400);
    ctxp = (float*)(wsb + 100966656);
    gemm_k<256, 512, true, true, false, 512>
        <<<dim3(512, 4), blk, 0, stream>>>(nullptr, W1, b1, embed, seq, act1);
    gemm_k<512, 256, false, false, true, 256>
        <<<dim3(512, 2), blk, 0, stream>>>(act1, W2, b2, embed, seq, X);
  } else {
    // fallback: 4 row-chunks of 8192 (act1 reused per chunk)
    float* act1 = (float*)(wsb);
    X = (float*)(wsb + 16777216);
    wbit = (int*)(wsb + 50331648);
    dscp = (float*)(wsb + 50462720);
    ftokp = (int*)(wsb + 50593792);
    stokp = (int*)(wsb + 50601984);
    cntp = (int*)(wsb + 50634752);
    ctxp = (float*)(wsb + 50635008);
    for (int c = 0; c < 4; ++c) {
      int row0 = c * 8192;
      gemm_k<256, 512, true, true, false, 512>
          <<<dim3(128, 4), blk, 0, stream>>>(nullptr, W1, b1, embed, seq + row0,
                                             act1);
      gemm_k<512, 256, false, false, true, 256>
          <<<dim3(128, 2), blk, 0, stream>>>(act1, W2, b2, embed, seq + row0,
                                             X + (size_t)row0 * 256);
    }
  }

  ln_k<<<8192, blk, 0, stream>>>(X, gamma, beta, Wg, bg, Wd, bd, wbit, dscp);
  select_k<<<32, dim3(1024), 0, stream>>>(wbit, dscp, ftokp, stokp, cntp);
  attn2_k<<<32, dim3(1024), 0, stream>>>(X, Wq, bq, ftokp, stokp, cntp, ctxp,
                                         out + (size_t)32 * 32000);
  logits2_k<<<dim3(125, 4), blk, 0, stream>>>(ctxp, Wo, bo, out);
}

// Round 5
// 199.153 us; speedup vs baseline: 3.6233x; 1.6539x over previous
//
#include <hip/hip_runtime.h>
#include <hip/hip_bf16.h>
#include <cstdint>

#define NEGV -1e9f

typedef __attribute__((ext_vector_type(8))) short short8v;  // 8 bf16 = 4 VGPR
typedef __attribute__((ext_vector_type(4))) float f32x4;

// ---------------- wave helpers (wave64) ----------------
__device__ __forceinline__ float wred_sum(float v) {
#pragma unroll
  for (int o = 32; o; o >>= 1) v += __shfl_xor(v, o);
  return v;
}
__device__ __forceinline__ float wred_max(float v) {
#pragma unroll
  for (int o = 32; o; o >>= 1) v = fmaxf(v, __shfl_xor(v, o));
  return v;
}
template <int CTRL>
__device__ __forceinline__ float dpp_fadd(float x) {
  int xi = __float_as_int(x);
  int yi = __builtin_amdgcn_update_dpp(xi, xi, CTRL, 0xF, 0xF, false);
  return x + __int_as_float(yi);
}
__device__ __forceinline__ float dpp_sum63(float v) {
  v = dpp_fadd<0xB1>(v);
  v = dpp_fadd<0x4E>(v);
  v = dpp_fadd<0x141>(v);
  v = dpp_fadd<0x140>(v);
  v = dpp_fadd<0x142>(v);
  v = dpp_fadd<0x143>(v);
  return v;  // lane 63 holds the total
}

// ---------------- bf16 split helpers (RNE) ----------------
__device__ __forceinline__ ushort bf16hi(float x) {
  unsigned u = __float_as_uint(x);
  unsigned r = u + 0x7FFFu + ((u >> 16) & 1u);
  return (ushort)(r >> 16);
}
__device__ __forceinline__ float bf16tof(ushort u) {
  return __uint_as_float(((unsigned)u) << 16);
}

// ---------------- W transpose + split: Wt_h/l[n][k] = split(W[k][n]) -------
__global__ __launch_bounds__(256) void wprep_k(const float* __restrict__ W,
                                               ushort* __restrict__ Wth,
                                               ushort* __restrict__ Wtl,
                                               int K, int N) {
  __shared__ float tile[32][33];
  const int k0 = blockIdx.x * 32, n0 = blockIdx.y * 32;
  const int r = threadIdx.x >> 5, c = threadIdx.x & 31;
#pragma unroll
  for (int i = 0; i < 4; ++i)
    tile[r + i * 8][c] = W[(size_t)(k0 + r + i * 8) * N + n0 + c];
  __syncthreads();
#pragma unroll
  for (int i = 0; i < 4; ++i) {
    const int rn = r + i * 8;
    const float x = tile[c][rn];  // W[k0+c][n0+rn]
    const ushort h = bf16hi(x);
    const ushort l = bf16hi(x - bf16tof(h));
    const size_t o = (size_t)(n0 + rn) * K + k0 + c;
    Wth[o] = h;
    Wtl[o] = l;
  }
}

// ---------------- split-bf16 3-pass MFMA GEMM ------------------------------
// C = A@B (+bias, epilogue variants). A: [M][K] fp32-equivalent via hi+lo
// bf16 split; B pre-transposed+split Bt[n][k]. acc += Ah*Bh + Ah*Bl + Al*Bh
// -> ~2^-16 relative error. Tiles 128x128, BK=64, 4 waves of 4x4 16x16x32
// frags. LDS [row][k] bf16 with 16B-chunk XOR swizzle (chunk ^= row&7):
// write+read use the same involution; frag reads land 2-way = free (m136).
// GATHER1: A row = embed[seq[m]] fp32, split inline; epilogue relu(acc+b)
//          stored as split pair (outh/outl).
// else:    A from split pair (Ath/Atl), pure copy; epilogue acc+b -> fp32.
template <int KDIM, int NDIM, bool GATHER1>
__global__ __launch_bounds__(256, 2) void mfma_gemm_k(
    const float* __restrict__ embed, const int* __restrict__ seq,
    const ushort* __restrict__ Ath, const ushort* __restrict__ Atl,
    const ushort* __restrict__ Bth, const ushort* __restrict__ Btl,
    const float* __restrict__ bias, float* __restrict__ outf,
    ushort* __restrict__ outh, ushort* __restrict__ outl) {
  __shared__ alignas(16) ushort Ah[8192], Al[8192], Bh[8192], Bl[8192];
  __shared__ int sidx[128];
  const int tid = threadIdx.x;
  const int m0 = blockIdx.x * 128, n0 = blockIdx.y * 128;
  if (GATHER1) {
    if (tid < 128) sidx[tid] = seq[m0 + tid];
  }
  __syncthreads();
  const int lane = tid & 63, wid = tid >> 6;
  const int wm = (wid >> 1) * 64, wn = (wid & 1) * 64;
  const int r15 = lane & 15, khalf = lane >> 4;

  f32x4 acc[4][4];
#pragma unroll
  for (int i = 0; i < 4; ++i)
#pragma unroll
    for (int j = 0; j < 4; ++j) acc[i][j] = (f32x4){0.f, 0.f, 0.f, 0.f};

#pragma unroll 1
  for (int k0 = 0; k0 < KDIM; k0 += 64) {
    // ---- stage A (128 rows x 64 k) ----
#pragma unroll
    for (int i = 0; i < 4; ++i) {
      const int q = tid + i * 256;
      const int row = q >> 3, kq = q & 7;
      const int off = (row * 8 + (kq ^ (row & 7))) * 8;
      if (GATHER1) {
        const float* ap = embed + (size_t)sidx[row] * 256 + k0 + kq * 8;
        const float4 x0 = *(const float4*)ap;
        const float4 x1 = *(const float4*)(ap + 4);
        const float xs[8] = {x0.x, x0.y, x0.z, x0.w, x1.x, x1.y, x1.z, x1.w};
        short8v vh, vl;
#pragma unroll
        for (int j = 0; j < 8; ++j) {
          const ushort h = bf16hi(xs[j]);
          vh[j] = (short)h;
          vl[j] = (short)bf16hi(xs[j] - bf16tof(h));
        }
        *(short8v*)&Ah[off] = vh;
        *(short8v*)&Al[off] = vl;
      } else {
        const size_t so = (size_t)(m0 + row) * KDIM + k0 + kq * 8;
        *(short8v*)&Ah[off] = *(const short8v*)&Ath[so];
        *(short8v*)&Al[off] = *(const short8v*)&Atl[so];
      }
    }
    // ---- stage B (128 n-rows x 64 k, pure copy from pre-split Bt) ----
#pragma unroll
    for (int i = 0; i < 4; ++i) {
      const int q = tid + i * 256;
      const int row = q >> 3, kq = q & 7;
      const size_t so = (size_t)(n0 + row) * KDIM + k0 + kq * 8;
      const int off = (row * 8 + (kq ^ (row & 7))) * 8;
      *(short8v*)&Bh[off] = *(const short8v*)&Bth[so];
      *(short8v*)&Bl[off] = *(const short8v*)&Btl[so];
    }
    __syncthreads();
    // ---- MFMA: 2 k-subtiles of 32 ----
#pragma unroll
    for (int ks = 0; ks < 2; ++ks) {
      const int kq = ks * 4 + khalf;
      short8v ah[4], al[4], bh[4], bl[4];
#pragma unroll
      for (int t = 0; t < 4; ++t) {
        const int ra = wm + t * 16 + r15;
        const int oa = (ra * 8 + (kq ^ (ra & 7))) * 8;
        ah[t] = *(const short8v*)&Ah[oa];
        al[t] = *(const short8v*)&Al[oa];
        const int rb = wn + t * 16 + r15;
        const int ob = (rb * 8 + (kq ^ (rb & 7))) * 8;
        bh[t] = *(const short8v*)&Bh[ob];
        bl[t] = *(const short8v*)&Bl[ob];
      }
#pragma unroll
      for (int mi = 0; mi < 4; ++mi)
#pragma unroll
        for (int ni = 0; ni < 4; ++ni) {
          acc[mi][ni] = __builtin_amdgcn_mfma_f32_16x16x32_bf16(
              ah[mi], bh[ni], acc[mi][ni], 0, 0, 0);
          acc[mi][ni] = __builtin_amdgcn_mfma_f32_16x16x32_bf16(
              ah[mi], bl[ni], acc[mi][ni], 0, 0, 0);
          acc[mi][ni] = __builtin_amdgcn_mfma_f32_16x16x32_bf16(
              al[mi], bh[ni], acc[mi][ni], 0, 0, 0);
        }
    }
    __syncthreads();
  }

  // ---- epilogue (C/D layout m89: col=lane&15, row=(lane>>4)*4+j) ----
#pragma unroll
  for (int ni = 0; ni < 4; ++ni) {
    const int n = n0 + wn + ni * 16 + r15;
    const float bv = bias[n];
#pragma unroll
    for (int mi = 0; mi < 4; ++mi) {
      const int mbase = m0 + wm + mi * 16 + khalf * 4;
#pragma unroll
      for (int j = 0; j < 4; ++j) {
        float t = acc[mi][ni][j] + bv;
        if (GATHER1) {
          t = fmaxf(t, 0.f);
          const ushort h = bf16hi(t);
          const ushort l = bf16hi(t - bf16tof(h));
          const size_t o = (size_t)(mbase + j) * NDIM + n;
          outh[o] = h;
          outl[o] = l;
        } else {
          outf[(size_t)(mbase + j) * NDIM + n] = t;
        }
      }
    }
  }
}

// ---------------- LayerNorm (X = ff; adds residual) + gate/demotion --------
__global__ __launch_bounds__(256) void ln_k(
    float* __restrict__ X, const int* __restrict__ seq,
    const float* __restrict__ embed, const float* __restrict__ gamma,
    const float* __restrict__ beta, const float* __restrict__ Wg,
    const float* __restrict__ bg, const float* __restrict__ Wd,
    const float* __restrict__ bd, int* __restrict__ wbit,
    float* __restrict__ dsc) {
  const int row = blockIdx.x * 4 + (threadIdx.x >> 6);
  const int lane = threadIdx.x & 63;
  float* xp = X + (size_t)row * 256 + lane * 4;
  float4 x = *(float4*)xp;
  const float4 e = *(const float4*)(embed + (size_t)seq[row] * 256 + lane * 4);
  x.x += e.x; x.y += e.y; x.z += e.z; x.w += e.w;  // h0 + ff (commutative)
  float s = (x.x + x.y) + (x.z + x.w);
  s = wred_sum(s);
  float mu = s * (1.f / 256.f);
  float dx0 = x.x - mu, dx1 = x.y - mu, dx2 = x.z - mu, dx3 = x.w - mu;
  float v = (dx0 * dx0 + dx1 * dx1) + (dx2 * dx2 + dx3 * dx3);
  v = wred_sum(v);
  float rstd = 1.f / sqrtf(v * (1.f / 256.f) + 1e-5f);
  float4 g4 = *(const float4*)(gamma + lane * 4);
  float4 b4 = *(const float4*)(beta + lane * 4);
  float4 y;
  y.x = dx0 * rstd * g4.x + b4.x;
  y.y = dx1 * rstd * g4.y + b4.y;
  y.z = dx2 * rstd * g4.z + b4.z;
  y.w = dx3 * rstd * g4.w + b4.w;
  *(float4*)xp = y;
  float4 wg4 = *(const float4*)(Wg + lane * 4);
  float4 wd4 = *(const float4*)(Wd + lane * 4);
  float gs = (y.x * wg4.x + y.y * wg4.y) + (y.z * wg4.z + y.w * wg4.w);
  float dsv = (y.x * wd4.x + y.y * wd4.y) + (y.z * wd4.z + y.w * wd4.w);
  gs = wred_sum(gs);
  dsv = wred_sum(dsv);
  if (lane == 0) {
    float xg = gs + bg[0];
    float sig;
    if (xg >= 0.f) {
      sig = 1.f / (1.f + expf(-xg));
    } else {
      float e2 = expf(xg);
      sig = e2 / (1.f + e2);
    }
    wbit[row] = (sig >= 0.4f) ? 1 : 0;
    dsc[row] = dsv + bd[0];
  }
}

// ---------------- offline LRU selection ------------------------------------
// E_k (evicted multiset after k demotions) = k smallest of first 63+k writes.
// fast = last write + 63 largest of first W-1; slow = E_K \ E_{K-256}.
__global__ __launch_bounds__(1024) void select_k(
    const int* __restrict__ wbit, const float* __restrict__ dsc,
    int* __restrict__ ftok, int* __restrict__ stok, int* __restrict__ cnt) {
  const int b = blockIdx.x;
  const int tid = threadIdx.x;
  const int lane = tid & 63, wv = tid >> 6;
  __shared__ unsigned long long skey[1024];
  __shared__ int stokl[1024];
  __shared__ int wavecnt[16];
  __shared__ int waveoff[17];
  __shared__ int fcnt_s[16], scnt_s[16];
  __shared__ int foff[16], soff[16];

  const int t = tid;
  int flag = 0;
  float d = 0.f;
  if (t < 1021) {
    flag = wbit[b * 1024 + t];
    d = dsc[b * 1024 + t];
  }
  const unsigned long long m = __ballot(flag != 0);
  if (lane == 0) wavecnt[wv] = __popcll(m);
  __syncthreads();
  if (tid == 0) {
    int acc = 0;
    for (int i = 0; i < 16; ++i) { waveoff[i] = acc; acc += wavecnt[i]; }
    waveoff[16] = acc;
  }
  __syncthreads();
  const int W = waveoff[16];
  if (flag) {
    unsigned u = __float_as_uint(d);
    u = (u & 0x80000000u) ? ~u : (u | 0x80000000u);
    const int w = waveoff[wv] + __popcll(m & ((1ull << lane) - 1ull));
    skey[w] = ((unsigned long long)u << 32) | (unsigned)w;
    stokl[w] = t;
  }
  __syncthreads();

  const int K = W - 64;
  const int end2 = max(0, W - 257);
  const int endAll = W - 1;
  bool fastf = false, slowf = false;
  if (tid < W) {
    const unsigned long long ki = skey[tid];
    int r1 = 0, r2 = 0;
    int j = 0;
    for (; j < end2; ++j) {
      const int lt = skey[j] < ki;
      r1 += lt;
      r2 += lt;
    }
    for (; j < endAll; ++j) r1 += (skey[j] < ki);
    const bool isLast = (tid == W - 1);
    const bool inEK = (!isLast) && (r1 < K);
    const bool inE2 = (tid < end2) && (r2 < K - 256);
    fastf = isLast || (!isLast && r1 >= K);
    slowf = inEK && !inE2;
  }

  const unsigned long long mf = __ballot(fastf);
  const unsigned long long ms = __ballot(slowf);
  if (lane == 0) { fcnt_s[wv] = __popcll(mf); scnt_s[wv] = __popcll(ms); }
  __syncthreads();
  if (tid == 0) {
    int a = 0, c = 0;
    for (int i = 0; i < 16; ++i) {
      foff[i] = a; a += fcnt_s[i];
      soff[i] = c; c += scnt_s[i];
    }
  }
  __syncthreads();
  if (fastf) {
    const int p = foff[wv] + __popcll(mf & ((1ull << lane) - 1ull));
    ftok[b * 64 + p] = stokl[tid];
  }
  if (slowf) {
    const int p = soff[wv] + __popcll(ms & ((1ull << lane) - 1ull));
    stok[b * 256 + p] = stokl[tid];
  }
  if (tid == 0) {
    cnt[b * 2] = W;
    cnt[b * 2 + 1] = max(K, 0);
  }
}

// ---------------- fused q + dual attention + ctx + need_slow, 16 waves ----
__global__ __launch_bounds__(1024) void attn2_k(
    const float* __restrict__ X, const float* __restrict__ Wq,
    const float* __restrict__ bq, const int* __restrict__ ftok,
    const int* __restrict__ stok, const int* __restrict__ cnt,
    float* __restrict__ ctx, float* __restrict__ needs_out) {
  const int b = blockIdx.x;
  const int tid = threadIdx.x;
  const int lane = tid & 63, wv = tid >> 6;
  __shared__ float hl[256], q[256];
  __shared__ float qpart[4][256];
  __shared__ float sc_f[64], at_f[64];
  __shared__ float sc_s[256], at_s[256];
  __shared__ int ft[64], st[256];
  __shared__ float redm[4], reds[4];
  __shared__ float needs_s;
  __shared__ float cpart[16][256];
  const float* Xb = X + (size_t)b * 1024 * 256;
  if (tid < 256) hl[tid] = Xb[(size_t)1023 * 256 + tid];
  else if (tid < 320) ft[tid - 256] = ftok[b * 64 + tid - 256];
  else if (tid < 576) st[tid - 320] = stok[b * 256 + tid - 320];
  __syncthreads();
  const int nf = min(cnt[b * 2], 64);
  const int ns = min(cnt[b * 2 + 1], 256);

  {
    const int col = tid & 255, kc = tid >> 8;
    float a = 0.f;
    const float* wp = Wq + (size_t)(kc * 64) * 256 + col;
#pragma unroll 4
    for (int k = 0; k < 64; ++k) a = fmaf(hl[kc * 64 + k], wp[(size_t)k * 256], a);
    qpart[kc][col] = a;
  }
  __syncthreads();
  if (tid < 256)
    q[tid] = ((qpart[0][tid] + qpart[1][tid]) + qpart[2][tid]) + qpart[3][tid] +
             bq[tid];
  __syncthreads();

  const float4 qq = *(const float4*)(q + lane * 4);
#pragma unroll 2
  for (int i = 0; i < 20; ++i) {
    const int r = wv + 16 * i;
    bool valid;
    int tok;
    if (r < 64) { valid = r < nf; tok = valid ? ft[r] : 0; }
    else        { valid = (r - 64) < ns; tok = valid ? st[r - 64] : 0; }
    float sc = NEGV;
    if (valid) {
      const float4 xr = *(const float4*)(Xb + (size_t)tok * 256 + lane * 4);
      float p = (xr.x * qq.x + xr.y * qq.y) + (xr.z * qq.z + xr.w * qq.w);
      sc = dpp_sum63(p);
    }
    if (lane == 63) {
      if (r < 64) sc_f[r] = sc;
      else sc_s[r - 64] = sc;
    }
  }
  __syncthreads();

  if (wv < 4) {
    float s = sc_s[tid];
    float mx = wred_max(s);
    if (lane == 0) redm[wv] = mx;
  } else if (wv == 8) {
    float s = sc_f[lane];
    float mx = wred_max(s);
    float e = expf(s - mx);
    float sm = wred_sum(e);
    float a = e / sm;
    at_f[lane] = a;
    float ma = wred_max(a);
    if (lane == 0) needs_s = (ma < 0.3f) ? 1.f : 0.f;
  }
  __syncthreads();
  if (wv < 4) {
    float s = sc_s[tid];
    float mx = fmaxf(fmaxf(redm[0], redm[1]), fmaxf(redm[2], redm[3]));
    float e = expf(s - mx);
    float sm = wred_sum(e);
    if (lane == 0) reds[wv] = sm;
    at_s[tid] = e;
  }
  __syncthreads();
  if (tid < 256) {
    float sm = (reds[0] + reds[1]) + (reds[2] + reds[3]);
    at_s[tid] = at_s[tid] / sm;
  }
  __syncthreads();

  const float needs = needs_s;
  float4 cp = {0.f, 0.f, 0.f, 0.f};
#pragma unroll 2
  for (int i = 0; i < 20; ++i) {
    const int r = wv + 16 * i;
    bool valid;
    int tok;
    float a;
    if (r < 64) { valid = r < nf; tok = valid ? ft[r] : 0; a = at_f[r]; }
    else {
      valid = (r - 64) < ns;
      tok = valid ? st[r - 64] : 0;
      a = needs * at_s[r - 64];
    }
    if (valid) {
      const float4 xr = *(const float4*)(Xb + (size_t)tok * 256 + lane * 4);
      cp.x = fmaf(a, xr.x, cp.x);
      cp.y = fmaf(a, xr.y, cp.y);
      cp.z = fmaf(a, xr.z, cp.z);
      cp.w = fmaf(a, xr.w, cp.w);
    }
  }
  *(float4*)&cpart[wv][lane * 4] = cp;
  __syncthreads();
  if (tid < 256) {
    float c = 0.f;
#pragma unroll
    for (int w = 0; w < 16; ++w) c += cpart[w][tid];
    ctx[b * 256 + tid] = c;
  }
  if (tid == 0) needs_out[b] = needs;
}

// ---------------- logits = ctx @ Wo + bo, grid (125,4) ----------------------
__global__ __launch_bounds__(256) void logits2_k(
    const float* __restrict__ ctx, const float* __restrict__ Wo,
    const float* __restrict__ bo, float* __restrict__ out) {
  __shared__ float cs[256 * 8];
  const int tid = threadIdx.x;
  const int b0 = blockIdx.y * 8;
  for (int i = tid; i < 2048; i += 256) {
    int bb = i & 7, hh = i >> 3;
    cs[hh * 8 + bb] = ctx[(b0 + bb) * 256 + hh];
  }
  __syncthreads();
  const int v = blockIdx.x * 256 + tid;
  float acc[8] = {0.f, 0.f, 0.f, 0.f, 0.f, 0.f, 0.f, 0.f};
#pragma unroll 4
  for (int h = 0; h < 256; ++h) {
    float wv = Wo[(size_t)h * 32000 + v];
#pragma unroll
    for (int bb = 0; bb < 8; ++bb) acc[bb] = fmaf(cs[h * 8 + bb], wv, acc[bb]);
  }
  float bv = bo[v];
#pragma unroll
  for (int bb = 0; bb < 8; ++bb)
    out[(size_t)(b0 + bb) * 32000 + v] = acc[bb] + bv;
}

extern "C" void kernel_launch(void* const* d_in, const int* in_sizes, int n_in,
                              void* d_out, int out_size, void* d_ws,
                              size_t ws_size, hipStream_t stream) {
  const int* seq = (const int*)d_in[0];
  const float* embed = (const float*)d_in[1];
  const float* W1 = (const float*)d_in[2];
  const float* b1 = (const float*)d_in[3];
  const float* W2 = (const float*)d_in[4];
  const float* b2 = (const float*)d_in[5];
  const float* gamma = (const float*)d_in[6];
  const float* beta = (const float*)d_in[7];
  const float* Wg = (const float*)d_in[8];
  const float* bg = (const float*)d_in[9];
  const float* Wd = (const float*)d_in[10];
  const float* bd = (const float*)d_in[11];
  const float* Wq = (const float*)d_in[12];
  const float* bq = (const float*)d_in[13];
  const float* Wo = (const float*)d_in[14];
  const float* bo = (const float*)d_in[15];
  float* out = (float*)d_out;

  char* wsb = (char*)d_ws;
  // layout (bytes): act1h 16 MiB | act1l 16 MiB | X 32 MiB | Wt 1 MiB | misc
  ushort* act1h = (ushort*)(wsb);                 // 16384*512*2
  ushort* act1l = (ushort*)(wsb + 16777216);
  float* X = (float*)(wsb + 33554432);            // 32768*256*4
  ushort* W1th = (ushort*)(wsb + 67108864);       // 512*256*2
  ushort* W1tl = (ushort*)(wsb + 67371008);
  ushort* W2th = (ushort*)(wsb + 67633152);       // 256*512*2
  ushort* W2tl = (ushort*)(wsb + 67895296);
  int* wbit = (int*)(wsb + 68157440);
  float* dscp = (float*)(wsb + 68288512);
  int* ftokp = (int*)(wsb + 68419584);
  int* stokp = (int*)(wsb + 68427776);
  int* cntp = (int*)(wsb + 68460544);
  float* ctxp = (float*)(wsb + 68460800);

  dim3 blk(256);
  wprep_k<<<dim3(8, 16), blk, 0, stream>>>(W1, W1th, W1tl, 256, 512);
  wprep_k<<<dim3(16, 8), blk, 0, stream>>>(W2, W2th, W2tl, 512, 256);

  for (int c = 0; c < 2; ++c) {
    const int* seqc = seq + c * 16384;
    mfma_gemm_k<256, 512, true><<<dim3(128, 4), blk, 0, stream>>>(
        embed, seqc, nullptr, nullptr, W1th, W1tl, b1, nullptr, act1h, act1l);
    mfma_gemm_k<512, 256, false><<<dim3(128, 2), blk, 0, stream>>>(
        nullptr, nullptr, act1h, act1l, W2th, W2tl, b2,
        X + (size_t)c * 16384 * 256, nullptr, nullptr);
  }

  ln_k<<<8192, blk, 0, stream>>>(X, seq, embed, gamma, beta, Wg, bg, Wd, bd,
                                 wbit, dscp);
  select_k<<<32, dim3(1024), 0, stream>>>(wbit, dscp, ftokp, stokp, cntp);
  attn2_k<<<32, dim3(1024), 0, stream>>>(X, Wq, bq, ftokp, stokp, cntp, ctxp,
                                         out + (size_t)32 * 32000);
  logits2_k<<<dim3(125, 4), blk, 0, stream>>>(ctxp, Wo, bo, out);
}

// Round 6
// 194.103 us; speedup vs baseline: 3.7175x; 1.0260x over previous
//
#include <hip/hip_runtime.h>
#include <hip/hip_bf16.h>
#include <cstdint>

#define NEGV -1e9f

typedef __attribute__((ext_vector_type(8))) short short8v;  // 8 bf16 = 4 VGPR
typedef __attribute__((ext_vector_type(4))) float f32x4;

// ---------------- wave helpers (wave64) ----------------
__device__ __forceinline__ float wred_sum(float v) {
#pragma unroll
  for (int o = 32; o; o >>= 1) v += __shfl_xor(v, o);
  return v;
}
__device__ __forceinline__ float wred_max(float v) {
#pragma unroll
  for (int o = 32; o; o >>= 1) v = fmaxf(v, __shfl_xor(v, o));
  return v;
}
template <int CTRL>
__device__ __forceinline__ float dpp_fadd(float x) {
  int xi = __float_as_int(x);
  int yi = __builtin_amdgcn_update_dpp(xi, xi, CTRL, 0xF, 0xF, false);
  return x + __int_as_float(yi);
}
__device__ __forceinline__ float dpp_sum63(float v) {
  v = dpp_fadd<0xB1>(v);
  v = dpp_fadd<0x4E>(v);
  v = dpp_fadd<0x141>(v);
  v = dpp_fadd<0x140>(v);
  v = dpp_fadd<0x142>(v);
  v = dpp_fadd<0x143>(v);
  return v;  // lane 63 holds the total
}

// ---------------- bf16 split helpers (RNE) ----------------
__device__ __forceinline__ ushort bf16hi(float x) {
  unsigned u = __float_as_uint(x);
  unsigned r = u + 0x7FFFu + ((u >> 16) & 1u);
  return (ushort)(r >> 16);
}
__device__ __forceinline__ float bf16tof(ushort u) {
  return __uint_as_float(((unsigned)u) << 16);
}

// async global->LDS, 16B per lane; LDS dest is wave-uniform base + lane*16
__device__ __forceinline__ void gload_lds16(const void* g, void* l) {
  __builtin_amdgcn_global_load_lds(
      (const __attribute__((address_space(1))) unsigned int*)g,
      (__attribute__((address_space(3))) unsigned int*)l, 16, 0, 0);
}

// ---------------- W transpose + split: Wt_h/l[n][k] = split(W[k][n]) -------
__global__ __launch_bounds__(256) void wprep_k(const float* __restrict__ W,
                                               ushort* __restrict__ Wth,
                                               ushort* __restrict__ Wtl,
                                               int K, int N) {
  __shared__ float tile[32][33];
  const int k0 = blockIdx.x * 32, n0 = blockIdx.y * 32;
  const int r = threadIdx.x >> 5, c = threadIdx.x & 31;
#pragma unroll
  for (int i = 0; i < 4; ++i)
    tile[r + i * 8][c] = W[(size_t)(k0 + r + i * 8) * N + n0 + c];
  __syncthreads();
#pragma unroll
  for (int i = 0; i < 4; ++i) {
    const int rn = r + i * 8;
    const float x = tile[c][rn];  // W[k0+c][n0+rn]
    const ushort h = bf16hi(x);
    const ushort l = bf16hi(x - bf16tof(h));
    const size_t o = (size_t)(n0 + rn) * K + k0 + c;
    Wth[o] = h;
    Wtl[o] = l;
  }
}

// ---------------- split-bf16 3-pass MFMA GEMM ------------------------------
// C = A@B (+bias, epilogue variants). acc += Ah*Bh + Ah*Bl + Al*Bh
// (~2^-16 rel error). Tiles 128x128, BK=64, 4 waves x (4x4) 16x16x32 frags.
// LDS [row][kq chunks of 8 bf16] with 16B-chunk XOR swizzle: data (row,kq)
// lives at phys chunk kq^(row&7) (involution).
// Pure-copy stages use global_load_lds: linear wave-uniform LDS dest,
// per-lane INVERSE-swizzled global source (same involution) -> frag reads
// unchanged. GATHER1 A-stage (fp32 gather + split) stays manual.
template <int KDIM, int NDIM, bool GATHER1>
__global__ __launch_bounds__(256, 2) void mfma_gemm_k(
    const float* __restrict__ embed, const int* __restrict__ seq,
    const ushort* __restrict__ Ath, const ushort* __restrict__ Atl,
    const ushort* __restrict__ Bth, const ushort* __restrict__ Btl,
    const float* __restrict__ bias, float* __restrict__ outf,
    ushort* __restrict__ outh, ushort* __restrict__ outl) {
  __shared__ alignas(16) ushort Ah[8192], Al[8192], Bh[8192], Bl[8192];
  __shared__ int sidx[128];
  const int tid = threadIdx.x;
  const int m0 = blockIdx.x * 128, n0 = blockIdx.y * 128;
  if (GATHER1) {
    if (tid < 128) sidx[tid] = seq[m0 + tid];
  }
  __syncthreads();
  const int lane = tid & 63, wid = tid >> 6;
  const int wm = (wid >> 1) * 64, wn = (wid & 1) * 64;
  const int r15 = lane & 15, khalf = lane >> 4;

  f32x4 acc[4][4];
#pragma unroll
  for (int i = 0; i < 4; ++i)
#pragma unroll
    for (int j = 0; j < 4; ++j) acc[i][j] = (f32x4){0.f, 0.f, 0.f, 0.f};

#pragma unroll 1
  for (int k0 = 0; k0 < KDIM; k0 += 64) {
    // ---- stage A (128 rows x 64 k) ----
    if (GATHER1) {
#pragma unroll
      for (int i = 0; i < 4; ++i) {
        const int q = tid + i * 256;
        const int row = q >> 3, kq = q & 7;
        const int off = (row * 8 + (kq ^ (row & 7))) * 8;
        const float* ap = embed + (size_t)sidx[row] * 256 + k0 + kq * 8;
        const float4 x0 = *(const float4*)ap;
        const float4 x1 = *(const float4*)(ap + 4);
        const float xs[8] = {x0.x, x0.y, x0.z, x0.w, x1.x, x1.y, x1.z, x1.w};
        short8v vh, vl;
#pragma unroll
        for (int j = 0; j < 8; ++j) {
          const ushort h = bf16hi(xs[j]);
          vh[j] = (short)h;
          vl[j] = (short)bf16hi(xs[j] - bf16tof(h));
        }
        *(short8v*)&Ah[off] = vh;
        *(short8v*)&Al[off] = vl;
      }
    } else {
#pragma unroll
      for (int i = 0; i < 4; ++i) {
        const int cb = i * 256 + wid * 64;  // wave-uniform phys chunk base
        const int c = cb + lane;
        const int row = c >> 3;
        const int kql = (c & 7) ^ (row & 7);  // inverse swizzle on source
        const size_t so = (size_t)(m0 + row) * KDIM + k0 + kql * 8;
        gload_lds16(Ath + so, &Ah[cb * 8]);
        gload_lds16(Atl + so, &Al[cb * 8]);
      }
    }
    // ---- stage B (pure copy from pre-split Bt) ----
#pragma unroll
    for (int i = 0; i < 4; ++i) {
      const int cb = i * 256 + wid * 64;
      const int c = cb + lane;
      const int row = c >> 3;
      const int kql = (c & 7) ^ (row & 7);
      const size_t so = (size_t)(n0 + row) * KDIM + k0 + kql * 8;
      gload_lds16(Bth + so, &Bh[cb * 8]);
      gload_lds16(Btl + so, &Bl[cb * 8]);
    }
    __syncthreads();
    // ---- MFMA: 2 k-subtiles of 32 ----
#pragma unroll
    for (int ks = 0; ks < 2; ++ks) {
      const int kq = ks * 4 + khalf;
      short8v ah[4], al[4], bh[4], bl[4];
#pragma unroll
      for (int t = 0; t < 4; ++t) {
        const int ra = wm + t * 16 + r15;
        const int oa = (ra * 8 + (kq ^ (ra & 7))) * 8;
        ah[t] = *(const short8v*)&Ah[oa];
        al[t] = *(const short8v*)&Al[oa];
        const int rb = wn + t * 16 + r15;
        const int ob = (rb * 8 + (kq ^ (rb & 7))) * 8;
        bh[t] = *(const short8v*)&Bh[ob];
        bl[t] = *(const short8v*)&Bl[ob];
      }
#pragma unroll
      for (int mi = 0; mi < 4; ++mi)
#pragma unroll
        for (int ni = 0; ni < 4; ++ni) {
          acc[mi][ni] = __builtin_amdgcn_mfma_f32_16x16x32_bf16(
              ah[mi], bh[ni], acc[mi][ni], 0, 0, 0);
          acc[mi][ni] = __builtin_amdgcn_mfma_f32_16x16x32_bf16(
              ah[mi], bl[ni], acc[mi][ni], 0, 0, 0);
          acc[mi][ni] = __builtin_amdgcn_mfma_f32_16x16x32_bf16(
              al[mi], bh[ni], acc[mi][ni], 0, 0, 0);
        }
    }
    __syncthreads();
  }

  // ---- epilogue (C/D layout m89: col=lane&15, row=(lane>>4)*4+j) ----
#pragma unroll
  for (int ni = 0; ni < 4; ++ni) {
    const int n = n0 + wn + ni * 16 + r15;
    const float bv = bias[n];
#pragma unroll
    for (int mi = 0; mi < 4; ++mi) {
      const int mbase = m0 + wm + mi * 16 + khalf * 4;
#pragma unroll
      for (int j = 0; j < 4; ++j) {
        float t = acc[mi][ni][j] + bv;
        if (GATHER1) {
          t = fmaxf(t, 0.f);
          const ushort h = bf16hi(t);
          const ushort l = bf16hi(t - bf16tof(h));
          const size_t o = (size_t)(mbase + j) * NDIM + n;
          outh[o] = h;
          outl[o] = l;
        } else {
          outf[(size_t)(mbase + j) * NDIM + n] = t;
        }
      }
    }
  }
}

// ---------------- LayerNorm (X = ff; adds residual) + gate/demotion --------
__global__ __launch_bounds__(256) void ln_k(
    float* __restrict__ X, const int* __restrict__ seq,
    const float* __restrict__ embed, const float* __restrict__ gamma,
    const float* __restrict__ beta, const float* __restrict__ Wg,
    const float* __restrict__ bg, const float* __restrict__ Wd,
    const float* __restrict__ bd, int* __restrict__ wbit,
    float* __restrict__ dsc) {
  const int row = blockIdx.x * 4 + (threadIdx.x >> 6);
  const int lane = threadIdx.x & 63;
  float* xp = X + (size_t)row * 256 + lane * 4;
  float4 x = *(float4*)xp;
  const float4 e = *(const float4*)(embed + (size_t)seq[row] * 256 + lane * 4);
  x.x += e.x; x.y += e.y; x.z += e.z; x.w += e.w;  // h0 + ff (commutative)
  float s = (x.x + x.y) + (x.z + x.w);
  s = wred_sum(s);
  float mu = s * (1.f / 256.f);
  float dx0 = x.x - mu, dx1 = x.y - mu, dx2 = x.z - mu, dx3 = x.w - mu;
  float v = (dx0 * dx0 + dx1 * dx1) + (dx2 * dx2 + dx3 * dx3);
  v = wred_sum(v);
  float rstd = 1.f / sqrtf(v * (1.f / 256.f) + 1e-5f);
  float4 g4 = *(const float4*)(gamma + lane * 4);
  float4 b4 = *(const float4*)(beta + lane * 4);
  float4 y;
  y.x = dx0 * rstd * g4.x + b4.x;
  y.y = dx1 * rstd * g4.y + b4.y;
  y.z = dx2 * rstd * g4.z + b4.z;
  y.w = dx3 * rstd * g4.w + b4.w;
  *(float4*)xp = y;
  float4 wg4 = *(const float4*)(Wg + lane * 4);
  float4 wd4 = *(const float4*)(Wd + lane * 4);
  float gs = (y.x * wg4.x + y.y * wg4.y) + (y.z * wg4.z + y.w * wg4.w);
  float dsv = (y.x * wd4.x + y.y * wd4.y) + (y.z * wd4.z + y.w * wd4.w);
  gs = wred_sum(gs);
  dsv = wred_sum(dsv);
  if (lane == 0) {
    float xg = gs + bg[0];
    float sig;
    if (xg >= 0.f) {
      sig = 1.f / (1.f + expf(-xg));
    } else {
      float e2 = expf(xg);
      sig = e2 / (1.f + e2);
    }
    wbit[row] = (sig >= 0.4f) ? 1 : 0;
    dsc[row] = dsv + bd[0];
  }
}

// ---------------- offline LRU selection ------------------------------------
// E_k (evicted multiset after k demotions) = k smallest of first 63+k writes.
// fast = last write + 63 largest of first W-1; slow = E_K \ E_{K-256}.
__global__ __launch_bounds__(1024) void select_k(
    const int* __restrict__ wbit, const float* __restrict__ dsc,
    int* __restrict__ ftok, int* __restrict__ stok, int* __restrict__ cnt) {
  const int b = blockIdx.x;
  const int tid = threadIdx.x;
  const int lane = tid & 63, wv = tid >> 6;
  __shared__ unsigned long long skey[1024];
  __shared__ int stokl[1024];
  __shared__ int wavecnt[16];
  __shared__ int waveoff[17];
  __shared__ int fcnt_s[16], scnt_s[16];
  __shared__ int foff[16], soff[16];

  const int t = tid;
  int flag = 0;
  float d = 0.f;
  if (t < 1021) {
    flag = wbit[b * 1024 + t];
    d = dsc[b * 1024 + t];
  }
  const unsigned long long m = __ballot(flag != 0);
  if (lane == 0) wavecnt[wv] = __popcll(m);
  __syncthreads();
  if (tid == 0) {
    int acc = 0;
    for (int i = 0; i < 16; ++i) { waveoff[i] = acc; acc += wavecnt[i]; }
    waveoff[16] = acc;
  }
  __syncthreads();
  const int W = waveoff[16];
  if (flag) {
    unsigned u = __float_as_uint(d);
    u = (u & 0x80000000u) ? ~u : (u | 0x80000000u);
    const int w = waveoff[wv] + __popcll(m & ((1ull << lane) - 1ull));
    skey[w] = ((unsigned long long)u << 32) | (unsigned)w;
    stokl[w] = t;
  }
  __syncthreads();

  const int K = W - 64;
  const int end2 = max(0, W - 257);
  const int endAll = W - 1;
  bool fastf = false, slowf = false;
  if (tid < W) {
    const unsigned long long ki = skey[tid];
    int r1 = 0, r2 = 0;
    int j = 0;
    for (; j < end2; ++j) {
      const int lt = skey[j] < ki;
      r1 += lt;
      r2 += lt;
    }
    for (; j < endAll; ++j) r1 += (skey[j] < ki);
    const bool isLast = (tid == W - 1);
    const bool inEK = (!isLast) && (r1 < K);
    const bool inE2 = (tid < end2) && (r2 < K - 256);
    fastf = isLast || (!isLast && r1 >= K);
    slowf = inEK && !inE2;
  }

  const unsigned long long mf = __ballot(fastf);
  const unsigned long long ms = __ballot(slowf);
  if (lane == 0) { fcnt_s[wv] = __popcll(mf); scnt_s[wv] = __popcll(ms); }
  __syncthreads();
  if (tid == 0) {
    int a = 0, c = 0;
    for (int i = 0; i < 16; ++i) {
      foff[i] = a; a += fcnt_s[i];
      soff[i] = c; c += scnt_s[i];
    }
  }
  __syncthreads();
  if (fastf) {
    const int p = foff[wv] + __popcll(mf & ((1ull << lane) - 1ull));
    ftok[b * 64 + p] = stokl[tid];
  }
  if (slowf) {
    const int p = soff[wv] + __popcll(ms & ((1ull << lane) - 1ull));
    stok[b * 256 + p] = stokl[tid];
  }
  if (tid == 0) {
    cnt[b * 2] = W;
    cnt[b * 2 + 1] = max(K, 0);
  }
}

// ---------------- fused q + dual attention + ctx + need_slow, 16 waves ----
__global__ __launch_bounds__(1024) void attn2_k(
    const float* __restrict__ X, const float* __restrict__ Wq,
    const float* __restrict__ bq, const int* __restrict__ ftok,
    const int* __restrict__ stok, const int* __restrict__ cnt,
    float* __restrict__ ctx, float* __restrict__ needs_out) {
  const int b = blockIdx.x;
  const int tid = threadIdx.x;
  const int lane = tid & 63, wv = tid >> 6;
  __shared__ float hl[256], q[256];
  __shared__ float qpart[4][256];
  __shared__ float sc_f[64], at_f[64];
  __shared__ float sc_s[256], at_s[256];
  __shared__ int ft[64], st[256];
  __shared__ float redm[4], reds[4];
  __shared__ float needs_s;
  __shared__ float cpart[16][256];
  const float* Xb = X + (size_t)b * 1024 * 256;
  if (tid < 256) hl[tid] = Xb[(size_t)1023 * 256 + tid];
  else if (tid < 320) ft[tid - 256] = ftok[b * 64 + tid - 256];
  else if (tid < 576) st[tid - 320] = stok[b * 256 + tid - 320];
  __syncthreads();
  const int nf = min(cnt[b * 2], 64);
  const int ns = min(cnt[b * 2 + 1], 256);

  {
    const int col = tid & 255, kc = tid >> 8;
    float a = 0.f;
    const float* wp = Wq + (size_t)(kc * 64) * 256 + col;
#pragma unroll 4
    for (int k = 0; k < 64; ++k) a = fmaf(hl[kc * 64 + k], wp[(size_t)k * 256], a);
    qpart[kc][col] = a;
  }
  __syncthreads();
  if (tid < 256)
    q[tid] = ((qpart[0][tid] + qpart[1][tid]) + qpart[2][tid]) + qpart[3][tid] +
             bq[tid];
  __syncthreads();

  const float4 qq = *(const float4*)(q + lane * 4);
#pragma unroll 2
  for (int i = 0; i < 20; ++i) {
    const int r = wv + 16 * i;
    bool valid;
    int tok;
    if (r < 64) { valid = r < nf; tok = valid ? ft[r] : 0; }
    else        { valid = (r - 64) < ns; tok = valid ? st[r - 64] : 0; }
    float sc = NEGV;
    if (valid) {
      const float4 xr = *(const float4*)(Xb + (size_t)tok * 256 + lane * 4);
      float p = (xr.x * qq.x + xr.y * qq.y) + (xr.z * qq.z + xr.w * qq.w);
      sc = dpp_sum63(p);
    }
    if (lane == 63) {
      if (r < 64) sc_f[r] = sc;
      else sc_s[r - 64] = sc;
    }
  }
  __syncthreads();

  if (wv < 4) {
    float s = sc_s[tid];
    float mx = wred_max(s);
    if (lane == 0) redm[wv] = mx;
  } else if (wv == 8) {
    float s = sc_f[lane];
    float mx = wred_max(s);
    float e = expf(s - mx);
    float sm = wred_sum(e);
    float a = e / sm;
    at_f[lane] = a;
    float ma = wred_max(a);
    if (lane == 0) needs_s = (ma < 0.3f) ? 1.f : 0.f;
  }
  __syncthreads();
  if (wv < 4) {
    float s = sc_s[tid];
    float mx = fmaxf(fmaxf(redm[0], redm[1]), fmaxf(redm[2], redm[3]));
    float e = expf(s - mx);
    float sm = wred_sum(e);
    if (lane == 0) reds[wv] = sm;
    at_s[tid] = e;
  }
  __syncthreads();
  if (tid < 256) {
    float sm = (reds[0] + reds[1]) + (reds[2] + reds[3]);
    at_s[tid] = at_s[tid] / sm;
  }
  __syncthreads();

  const float needs = needs_s;
  float4 cp = {0.f, 0.f, 0.f, 0.f};
#pragma unroll 2
  for (int i = 0; i < 20; ++i) {
    const int r = wv + 16 * i;
    bool valid;
    int tok;
    float a;
    if (r < 64) { valid = r < nf; tok = valid ? ft[r] : 0; a = at_f[r]; }
    else {
      valid = (r - 64) < ns;
      tok = valid ? st[r - 64] : 0;
      a = needs * at_s[r - 64];
    }
    if (valid) {
      const float4 xr = *(const float4*)(Xb + (size_t)tok * 256 + lane * 4);
      cp.x = fmaf(a, xr.x, cp.x);
      cp.y = fmaf(a, xr.y, cp.y);
      cp.z = fmaf(a, xr.z, cp.z);
      cp.w = fmaf(a, xr.w, cp.w);
    }
  }
  *(float4*)&cpart[wv][lane * 4] = cp;
  __syncthreads();
  if (tid < 256) {
    float c = 0.f;
#pragma unroll
    for (int w = 0; w < 16; ++w) c += cpart[w][tid];
    ctx[b * 256 + tid] = c;
  }
  if (tid == 0) needs_out[b] = needs;
}

// ---------------- logits = ctx @ Wo + bo, grid (125,2), 16-deep ILP --------
__global__ __launch_bounds__(256) void logits3_k(
    const float* __restrict__ ctx, const float* __restrict__ Wo,
    const float* __restrict__ bo, float* __restrict__ out) {
  __shared__ float cs[256 * 16];  // [h][bb]
  const int tid = threadIdx.x;
  const int b0 = blockIdx.y * 16;
  for (int i = tid; i < 4096; i += 256) {
    int bb = i & 15, hh = i >> 4;
    cs[hh * 16 + bb] = ctx[(b0 + bb) * 256 + hh];
  }
  __syncthreads();
  const int v = blockIdx.x * 256 + tid;
  float acc[16];
#pragma unroll
  for (int i = 0; i < 16; ++i) acc[i] = 0.f;
  for (int h0 = 0; h0 < 256; h0 += 16) {
    float wv[16];
#pragma unroll
    for (int u = 0; u < 16; ++u) wv[u] = Wo[(size_t)(h0 + u) * 32000 + v];
#pragma unroll
    for (int u = 0; u < 16; ++u) {
      const float* cp = cs + (h0 + u) * 16;
#pragma unroll
      for (int bb = 0; bb < 16; ++bb) acc[bb] = fmaf(cp[bb], wv[u], acc[bb]);
    }
  }
  float bv = bo[v];
#pragma unroll
  for (int bb = 0; bb < 16; ++bb)
    out[(size_t)(b0 + bb) * 32000 + v] = acc[bb] + bv;
}

extern "C" void kernel_launch(void* const* d_in, const int* in_sizes, int n_in,
                              void* d_out, int out_size, void* d_ws,
                              size_t ws_size, hipStream_t stream) {
  const int* seq = (const int*)d_in[0];
  const float* embed = (const float*)d_in[1];
  const float* W1 = (const float*)d_in[2];
  const float* b1 = (const float*)d_in[3];
  const float* W2 = (const float*)d_in[4];
  const float* b2 = (const float*)d_in[5];
  const float* gamma = (const float*)d_in[6];
  const float* beta = (const float*)d_in[7];
  const float* Wg = (const float*)d_in[8];
  const float* bg = (const float*)d_in[9];
  const float* Wd = (const float*)d_in[10];
  const float* bd = (const float*)d_in[11];
  const float* Wq = (const float*)d_in[12];
  const float* bq = (const float*)d_in[13];
  const float* Wo = (const float*)d_in[14];
  const float* bo = (const float*)d_in[15];
  float* out = (float*)d_out;

  char* wsb = (char*)d_ws;
  // layout (bytes): act1h 16 MiB | act1l 16 MiB | X 32 MiB | Wt 1 MiB | misc
  ushort* act1h = (ushort*)(wsb);                 // 16384*512*2
  ushort* act1l = (ushort*)(wsb + 16777216);
  float* X = (float*)(wsb + 33554432);            // 32768*256*4
  ushort* W1th = (ushort*)(wsb + 67108864);       // 512*256*2
  ushort* W1tl = (ushort*)(wsb + 67371008);
  ushort* W2th = (ushort*)(wsb + 67633152);       // 256*512*2
  ushort* W2tl = (ushort*)(wsb + 67895296);
  int* wbit = (int*)(wsb + 68157440);
  float* dscp = (float*)(wsb + 68288512);
  int* ftokp = (int*)(wsb + 68419584);
  int* stokp = (int*)(wsb + 68427776);
  int* cntp = (int*)(wsb + 68460544);
  float* ctxp = (float*)(wsb + 68460800);

  dim3 blk(256);
  wprep_k<<<dim3(8, 16), blk, 0, stream>>>(W1, W1th, W1tl, 256, 512);
  wprep_k<<<dim3(16, 8), blk, 0, stream>>>(W2, W2th, W2tl, 512, 256);

  for (int c = 0; c < 2; ++c) {
    const int* seqc = seq + c * 16384;
    mfma_gemm_k<256, 512, true><<<dim3(128, 4), blk, 0, stream>>>(
        embed, seqc, nullptr, nullptr, W1th, W1tl, b1, nullptr, act1h, act1l);
    mfma_gemm_k<512, 256, false><<<dim3(128, 2), blk, 0, stream>>>(
        nullptr, nullptr, act1h, act1l, W2th, W2tl, b2,
        X + (size_t)c * 16384 * 256, nullptr, nullptr);
  }

  ln_k<<<8192, blk, 0, stream>>>(X, seq, embed, gamma, beta, Wg, bg, Wd, bd,
                                 wbit, dscp);
  select_k<<<32, dim3(1024), 0, stream>>>(wbit, dscp, ftokp, stokp, cntp);
  attn2_k<<<32, dim3(1024), 0, stream>>>(X, Wq, bq, ftokp, stokp, cntp, ctxp,
                                         out + (size_t)32 * 32000);
  logits3_k<<<dim3(125, 2), blk, 0, stream>>>(ctxp, Wo, bo, out);
}

// Round 7
// 183.906 us; speedup vs baseline: 3.9237x; 1.0554x over previous
//
#include <hip/hip_runtime.h>
#include <hip/hip_bf16.h>
#include <cstdint>

#define NEGV -1e9f

typedef __attribute__((ext_vector_type(8))) short short8v;  // 8 bf16 = 4 VGPR
typedef __attribute__((ext_vector_type(4))) float f32x4;

// ---------------- wave helpers (wave64) ----------------
__device__ __forceinline__ float wred_sum(float v) {
#pragma unroll
  for (int o = 32; o; o >>= 1) v += __shfl_xor(v, o);
  return v;
}
__device__ __forceinline__ float wred_max(float v) {
#pragma unroll
  for (int o = 32; o; o >>= 1) v = fmaxf(v, __shfl_xor(v, o));
  return v;
}
template <int CTRL>
__device__ __forceinline__ float dpp_fadd(float x) {
  int xi = __float_as_int(x);
  int yi = __builtin_amdgcn_update_dpp(xi, xi, CTRL, 0xF, 0xF, false);
  return x + __int_as_float(yi);
}
__device__ __forceinline__ float dpp_sum63(float v) {
  v = dpp_fadd<0xB1>(v);
  v = dpp_fadd<0x4E>(v);
  v = dpp_fadd<0x141>(v);
  v = dpp_fadd<0x140>(v);
  v = dpp_fadd<0x142>(v);
  v = dpp_fadd<0x143>(v);
  return v;  // lane 63 holds the total
}
// 16-lane (DPP-row) sum: every lane of each 16-group gets the group sum.
__device__ __forceinline__ float dpp_sum16(float v) {
  v = dpp_fadd<0xB1>(v);   // xor1
  v = dpp_fadd<0x4E>(v);   // xor2
  v = dpp_fadd<0x141>(v);  // row_half_mirror (xor4 after quads)
  v = dpp_fadd<0x140>(v);  // row_mirror (xor8)
  return v;
}

// ---------------- bf16 split helpers (RNE) ----------------
__device__ __forceinline__ ushort bf16hi(float x) {
  unsigned u = __float_as_uint(x);
  unsigned r = u + 0x7FFFu + ((u >> 16) & 1u);
  return (ushort)(r >> 16);
}
__device__ __forceinline__ float bf16tof(ushort u) {
  return __uint_as_float(((unsigned)u) << 16);
}

// async global->LDS, 16B per lane; LDS dest is wave-uniform base + lane*16
__device__ __forceinline__ void gload_lds16(const void* g, void* l) {
  __builtin_amdgcn_global_load_lds(
      (const __attribute__((address_space(1))) unsigned int*)g,
      (__attribute__((address_space(3))) unsigned int*)l, 16, 0, 0);
}

// ---------------- W transpose + split: Wt_h/l[n][k] = split(W[k][n]) -------
__global__ __launch_bounds__(256) void wprep_k(const float* __restrict__ W,
                                               ushort* __restrict__ Wth,
                                               ushort* __restrict__ Wtl,
                                               int K, int N) {
  __shared__ float tile[32][33];
  const int k0 = blockIdx.x * 32, n0 = blockIdx.y * 32;
  const int r = threadIdx.x >> 5, c = threadIdx.x & 31;
#pragma unroll
  for (int i = 0; i < 4; ++i)
    tile[r + i * 8][c] = W[(size_t)(k0 + r + i * 8) * N + n0 + c];
  __syncthreads();
#pragma unroll
  for (int i = 0; i < 4; ++i) {
    const int rn = r + i * 8;
    const float x = tile[c][rn];
    const ushort h = bf16hi(x);
    const ushort l = bf16hi(x - bf16tof(h));
    const size_t o = (size_t)(n0 + rn) * K + k0 + c;
    Wth[o] = h;
    Wtl[o] = l;
  }
}

// ---------------- GEMM1: act1 = split(relu(embed[seq]@W1 + b1)) ------------
// split-bf16 3-pass MFMA (acc += AhBh + AhBl + AlBh, ~2^-16 rel err).
// 128x128 tile, BK=64, 4 waves x (4x4) 16x16x32. LDS 16B-chunk XOR swizzle.
__global__ __launch_bounds__(256, 2) void gemm1_k(
    const float* __restrict__ embed, const int* __restrict__ seq,
    const ushort* __restrict__ Bth, const ushort* __restrict__ Btl,
    const float* __restrict__ bias, ushort* __restrict__ outh,
    ushort* __restrict__ outl) {
  __shared__ alignas(16) ushort Ah[8192], Al[8192], Bh[8192], Bl[8192];
  __shared__ int sidx[128];
  const int tid = threadIdx.x;
  const int m0 = blockIdx.x * 128, n0 = blockIdx.y * 128;
  if (tid < 128) sidx[tid] = seq[m0 + tid];
  __syncthreads();
  const int lane = tid & 63, wid = tid >> 6;
  const int wm = (wid >> 1) * 64, wn = (wid & 1) * 64;
  const int r15 = lane & 15, khalf = lane >> 4;

  f32x4 acc[4][4];
#pragma unroll
  for (int i = 0; i < 4; ++i)
#pragma unroll
    for (int j = 0; j < 4; ++j) acc[i][j] = (f32x4){0.f, 0.f, 0.f, 0.f};

#pragma unroll 1
  for (int k0 = 0; k0 < 256; k0 += 64) {
    // A: gather fp32 embed rows, split inline (manual staging)
#pragma unroll
    for (int i = 0; i < 4; ++i) {
      const int q = tid + i * 256;
      const int row = q >> 3, kq = q & 7;
      const int off = (row * 8 + (kq ^ (row & 7))) * 8;
      const float* ap = embed + (size_t)sidx[row] * 256 + k0 + kq * 8;
      const float4 x0 = *(const float4*)ap;
      const float4 x1 = *(const float4*)(ap + 4);
      const float xs[8] = {x0.x, x0.y, x0.z, x0.w, x1.x, x1.y, x1.z, x1.w};
      short8v vh, vl;
#pragma unroll
      for (int j = 0; j < 8; ++j) {
        const ushort h = bf16hi(xs[j]);
        vh[j] = (short)h;
        vl[j] = (short)bf16hi(xs[j] - bf16tof(h));
      }
      *(short8v*)&Ah[off] = vh;
      *(short8v*)&Al[off] = vl;
    }
    // B: pure copy via global_load_lds (linear dest + inverse-swz source)
#pragma unroll
    for (int i = 0; i < 4; ++i) {
      const int cb = i * 256 + wid * 64;
      const int c = cb + lane;
      const int row = c >> 3;
      const int kql = (c & 7) ^ (row & 7);
      const size_t so = (size_t)(n0 + row) * 256 + k0 + kql * 8;
      gload_lds16(Bth + so, &Bh[cb * 8]);
      gload_lds16(Btl + so, &Bl[cb * 8]);
    }
    __syncthreads();
#pragma unroll
    for (int ks = 0; ks < 2; ++ks) {
      const int kq = ks * 4 + khalf;
      short8v ahf[4], alf[4], bhf[4], blf[4];
#pragma unroll
      for (int t = 0; t < 4; ++t) {
        const int ra = wm + t * 16 + r15;
        const int oa = (ra * 8 + (kq ^ (ra & 7))) * 8;
        ahf[t] = *(const short8v*)&Ah[oa];
        alf[t] = *(const short8v*)&Al[oa];
        const int rb = wn + t * 16 + r15;
        const int ob = (rb * 8 + (kq ^ (rb & 7))) * 8;
        bhf[t] = *(const short8v*)&Bh[ob];
        blf[t] = *(const short8v*)&Bl[ob];
      }
#pragma unroll
      for (int mi = 0; mi < 4; ++mi)
#pragma unroll
        for (int ni = 0; ni < 4; ++ni) {
          acc[mi][ni] = __builtin_amdgcn_mfma_f32_16x16x32_bf16(
              ahf[mi], bhf[ni], acc[mi][ni], 0, 0, 0);
          acc[mi][ni] = __builtin_amdgcn_mfma_f32_16x16x32_bf16(
              ahf[mi], blf[ni], acc[mi][ni], 0, 0, 0);
          acc[mi][ni] = __builtin_amdgcn_mfma_f32_16x16x32_bf16(
              alf[mi], bhf[ni], acc[mi][ni], 0, 0, 0);
        }
    }
    __syncthreads();
  }
  // epilogue: relu(acc+b) -> split bf16 pair (C/D: col=lane&15, row=khalf*4+j)
#pragma unroll
  for (int ni = 0; ni < 4; ++ni) {
    const int n = n0 + wn + ni * 16 + r15;
    const float bv = bias[n];
#pragma unroll
    for (int mi = 0; mi < 4; ++mi) {
      const int mbase = m0 + wm + mi * 16 + khalf * 4;
#pragma unroll
      for (int j = 0; j < 4; ++j) {
        float t = fmaxf(acc[mi][ni][j] + bv, 0.f);
        const ushort h = bf16hi(t);
        const ushort l = bf16hi(t - bf16tof(h));
        const size_t o = (size_t)(mbase + j) * 512 + n;
        outh[o] = h;
        outl[o] = l;
      }
    }
  }
}

// ---------------- fused GEMM2 + residual + LayerNorm + gate/dsc ------------
// 128x256 tile (full N row per block), 8 waves (2m x 4n), K=512.
// x = (acc + b2) + embed[seq[m]]  (same add order as before).
// LN: two-phase (mean, then centered var) via DPP16 + LDS quadrant combine.
__global__ __launch_bounds__(512, 1) void gemm2ln_k(
    const ushort* __restrict__ Ath, const ushort* __restrict__ Atl,
    const ushort* __restrict__ Bth, const ushort* __restrict__ Btl,
    const float* __restrict__ b2, const int* __restrict__ seq,
    const float* __restrict__ embed, const float* __restrict__ gamma,
    const float* __restrict__ beta, const float* __restrict__ Wg,
    const float* __restrict__ bg, const float* __restrict__ Wd,
    const float* __restrict__ bd, float* __restrict__ X,
    int* __restrict__ wbit, float* __restrict__ dsc) {
  __shared__ alignas(16) ushort Ah[8192], Al[8192];    // 128 x 64
  __shared__ alignas(16) ushort Bh[16384], Bl[16384];  // 256 x 64
  __shared__ float par0[128][4], par1[128][4], gpar[128][4], dpar[128][4];
  __shared__ float g_s[256], be_s[256], wg_s[256], wd_s[256], b2_s[256];
  __shared__ int sidx[128];
  const int tid = threadIdx.x;  // 512
  const int m0 = blockIdx.x * 128;
  if (tid < 128) sidx[tid] = seq[m0 + tid];
  if (tid >= 256) {
    const int c = tid - 256;
    g_s[c] = gamma[c];
    be_s[c] = beta[c];
    wg_s[c] = Wg[c];
    wd_s[c] = Wd[c];
    b2_s[c] = b2[c];
  }
  const int lane = tid & 63, w = tid >> 6;  // 8 waves
  const int wm = (w >> 2) * 64, wn = (w & 3) * 64;
  const int r15 = lane & 15, khalf = lane >> 4;

  f32x4 acc[4][4];
#pragma unroll
  for (int i = 0; i < 4; ++i)
#pragma unroll
    for (int j = 0; j < 4; ++j) acc[i][j] = (f32x4){0.f, 0.f, 0.f, 0.f};

#pragma unroll 1
  for (int k0 = 0; k0 < 512; k0 += 64) {
    // A: 1024 16B chunks over 512 threads
#pragma unroll
    for (int i = 0; i < 2; ++i) {
      const int cb = i * 512 + w * 64;
      const int c = cb + lane;
      const int row = c >> 3;
      const int kql = (c & 7) ^ (row & 7);
      const size_t so = (size_t)(m0 + row) * 512 + k0 + kql * 8;
      gload_lds16(Ath + so, &Ah[cb * 8]);
      gload_lds16(Atl + so, &Al[cb * 8]);
    }
    // B (W2t): 2048 chunks
#pragma unroll
    for (int i = 0; i < 4; ++i) {
      const int cb = i * 512 + w * 64;
      const int c = cb + lane;
      const int row = c >> 3;  // n
      const int kql = (c & 7) ^ (row & 7);
      const size_t so = (size_t)row * 512 + k0 + kql * 8;
      gload_lds16(Bth + so, &Bh[cb * 8]);
      gload_lds16(Btl + so, &Bl[cb * 8]);
    }
    __syncthreads();
#pragma unroll
    for (int ks = 0; ks < 2; ++ks) {
      const int kq = ks * 4 + khalf;
      short8v ahf[4], alf[4], bhf[4], blf[4];
#pragma unroll
      for (int t = 0; t < 4; ++t) {
        const int ra = wm + t * 16 + r15;
        const int oa = (ra * 8 + (kq ^ (ra & 7))) * 8;
        ahf[t] = *(const short8v*)&Ah[oa];
        alf[t] = *(const short8v*)&Al[oa];
        const int rb = wn + t * 16 + r15;
        const int ob = (rb * 8 + (kq ^ (rb & 7))) * 8;
        bhf[t] = *(const short8v*)&Bh[ob];
        blf[t] = *(const short8v*)&Bl[ob];
      }
#pragma unroll
      for (int mi = 0; mi < 4; ++mi)
#pragma unroll
        for (int ni = 0; ni < 4; ++ni) {
          acc[mi][ni] = __builtin_amdgcn_mfma_f32_16x16x32_bf16(
              ahf[mi], bhf[ni], acc[mi][ni], 0, 0, 0);
          acc[mi][ni] = __builtin_amdgcn_mfma_f32_16x16x32_bf16(
              ahf[mi], blf[ni], acc[mi][ni], 0, 0, 0);
          acc[mi][ni] = __builtin_amdgcn_mfma_f32_16x16x32_bf16(
              alf[mi], bhf[ni], acc[mi][ni], 0, 0, 0);
        }
    }
    __syncthreads();
  }

  // ---- epilogue: x = (acc + b2) + resid; then LN + gate/dsc ----
  float mu_r[4][4];
#pragma unroll
  for (int mi = 0; mi < 4; ++mi)
#pragma unroll
    for (int j = 0; j < 4; ++j) {
      const int rowl = wm + mi * 16 + khalf * 4 + j;
      const float* ep = embed + (size_t)sidx[rowl] * 256;
#pragma unroll
      for (int ni = 0; ni < 4; ++ni) {
        const int col = wn + ni * 16 + r15;
        float t = acc[mi][ni][j] + b2_s[col];
        acc[mi][ni][j] = t + ep[col];
      }
      float s = (acc[mi][0][j] + acc[mi][1][j]) + (acc[mi][2][j] + acc[mi][3][j]);
      s = dpp_sum16(s);
      if (r15 == 0) par0[rowl][w & 3] = s;
    }
  __syncthreads();
#pragma unroll
  for (int mi = 0; mi < 4; ++mi)
#pragma unroll
    for (int j = 0; j < 4; ++j) {
      const int rowl = wm + mi * 16 + khalf * 4 + j;
      const float mu = ((par0[rowl][0] + par0[rowl][1]) +
                        (par0[rowl][2] + par0[rowl][3])) * (1.f / 256.f);
      mu_r[mi][j] = mu;
      const float d0 = acc[mi][0][j] - mu, d1 = acc[mi][1][j] - mu;
      const float d2 = acc[mi][2][j] - mu, d3 = acc[mi][3][j] - mu;
      float vv = (d0 * d0 + d1 * d1) + (d2 * d2 + d3 * d3);
      vv = dpp_sum16(vv);
      if (r15 == 0) par1[rowl][w & 3] = vv;
    }
  __syncthreads();
#pragma unroll
  for (int mi = 0; mi < 4; ++mi)
#pragma unroll
    for (int j = 0; j < 4; ++j) {
      const int rowl = wm + mi * 16 + khalf * 4 + j;
      const float mu = mu_r[mi][j];
      const float var = ((par1[rowl][0] + par1[rowl][1]) +
                         (par1[rowl][2] + par1[rowl][3])) * (1.f / 256.f);
      const float rstd = 1.f / sqrtf(var + 1e-5f);
      float ys[4], gw[4], dw[4];
#pragma unroll
      for (int ni = 0; ni < 4; ++ni) {
        const int col = wn + ni * 16 + r15;
        const float y = (acc[mi][ni][j] - mu) * rstd * g_s[col] + be_s[col];
        X[(size_t)(m0 + rowl) * 256 + col] = y;
        ys[ni] = y;
        gw[ni] = wg_s[col];
        dw[ni] = wd_s[col];
      }
      float gp = (ys[0] * gw[0] + ys[1] * gw[1]) + (ys[2] * gw[2] + ys[3] * gw[3]);
      float dp = (ys[0] * dw[0] + ys[1] * dw[1]) + (ys[2] * dw[2] + ys[3] * dw[3]);
      gp = dpp_sum16(gp);
      dp = dpp_sum16(dp);
      if (r15 == 0) {
        gpar[rowl][w & 3] = gp;
        dpar[rowl][w & 3] = dp;
      }
    }
  __syncthreads();
  if (tid < 128) {
    const int row = tid;
    const float gs = ((gpar[row][0] + gpar[row][1]) +
                      (gpar[row][2] + gpar[row][3])) + bg[0];
    const float dsv = ((dpar[row][0] + dpar[row][1]) +
                       (dpar[row][2] + dpar[row][3])) + bd[0];
    float sig;
    if (gs >= 0.f) {
      sig = 1.f / (1.f + expf(-gs));
    } else {
      const float e2 = expf(gs);
      sig = e2 / (1.f + e2);
    }
    wbit[m0 + row] = (sig >= 0.4f) ? 1 : 0;
    dsc[m0 + row] = dsv;
  }
}

// ---------------- offline LRU selection ------------------------------------
// E_k (evicted multiset after k demotions) = k smallest of first 63+k writes.
// fast = last write + 63 largest of first W-1; slow = E_K \ E_{K-256}.
__global__ __launch_bounds__(1024) void select_k(
    const int* __restrict__ wbit, const float* __restrict__ dsc,
    int* __restrict__ ftok, int* __restrict__ stok, int* __restrict__ cnt) {
  const int b = blockIdx.x;
  const int tid = threadIdx.x;
  const int lane = tid & 63, wv = tid >> 6;
  __shared__ unsigned long long skey[1024];
  __shared__ int stokl[1024];
  __shared__ int wavecnt[16];
  __shared__ int waveoff[17];
  __shared__ int fcnt_s[16], scnt_s[16];
  __shared__ int foff[16], soff[16];

  const int t = tid;
  int flag = 0;
  float d = 0.f;
  if (t < 1021) {
    flag = wbit[b * 1024 + t];
    d = dsc[b * 1024 + t];
  }
  const unsigned long long m = __ballot(flag != 0);
  if (lane == 0) wavecnt[wv] = __popcll(m);
  __syncthreads();
  if (tid == 0) {
    int acc = 0;
    for (int i = 0; i < 16; ++i) { waveoff[i] = acc; acc += wavecnt[i]; }
    waveoff[16] = acc;
  }
  __syncthreads();
  const int W = waveoff[16];
  if (flag) {
    unsigned u = __float_as_uint(d);
    u = (u & 0x80000000u) ? ~u : (u | 0x80000000u);
    const int w = waveoff[wv] + __popcll(m & ((1ull << lane) - 1ull));
    skey[w] = ((unsigned long long)u << 32) | (unsigned)w;
    stokl[w] = t;
  }
  __syncthreads();

  const int K = W - 64;
  const int end2 = max(0, W - 257);
  const int endAll = W - 1;
  bool fastf = false, slowf = false;
  if (tid < W) {
    const unsigned long long ki = skey[tid];
    int r1 = 0, r2 = 0;
    int j = 0;
    for (; j < end2; ++j) {
      const int lt = skey[j] < ki;
      r1 += lt;
      r2 += lt;
    }
    for (; j < endAll; ++j) r1 += (skey[j] < ki);
    const bool isLast = (tid == W - 1);
    const bool inEK = (!isLast) && (r1 < K);
    const bool inE2 = (tid < end2) && (r2 < K - 256);
    fastf = isLast || (!isLast && r1 >= K);
    slowf = inEK && !inE2;
  }

  const unsigned long long mf = __ballot(fastf);
  const unsigned long long ms = __ballot(slowf);
  if (lane == 0) { fcnt_s[wv] = __popcll(mf); scnt_s[wv] = __popcll(ms); }
  __syncthreads();
  if (tid == 0) {
    int a = 0, c = 0;
    for (int i = 0; i < 16; ++i) {
      foff[i] = a; a += fcnt_s[i];
      soff[i] = c; c += scnt_s[i];
    }
  }
  __syncthreads();
  if (fastf) {
    const int p = foff[wv] + __popcll(mf & ((1ull << lane) - 1ull));
    ftok[b * 64 + p] = stokl[tid];
  }
  if (slowf) {
    const int p = soff[wv] + __popcll(ms & ((1ull << lane) - 1ull));
    stok[b * 256 + p] = stokl[tid];
  }
  if (tid == 0) {
    cnt[b * 2] = W;
    cnt[b * 2 + 1] = max(K, 0);
  }
}

// ---------------- fused q + dual attention + ctx + need_slow, 16 waves ----
__global__ __launch_bounds__(1024) void attn2_k(
    const float* __restrict__ X, const float* __restrict__ Wq,
    const float* __restrict__ bq, const int* __restrict__ ftok,
    const int* __restrict__ stok, const int* __restrict__ cnt,
    float* __restrict__ ctx, float* __restrict__ needs_out) {
  const int b = blockIdx.x;
  const int tid = threadIdx.x;
  const int lane = tid & 63, wv = tid >> 6;
  __shared__ float hl[256], q[256];
  __shared__ float qpart[4][256];
  __shared__ float sc_f[64], at_f[64];
  __shared__ float sc_s[256], at_s[256];
  __shared__ int ft[64], st[256];
  __shared__ float redm[4], reds[4];
  __shared__ float needs_s;
  __shared__ float cpart[16][256];
  const float* Xb = X + (size_t)b * 1024 * 256;
  if (tid < 256) hl[tid] = Xb[(size_t)1023 * 256 + tid];
  else if (tid < 320) ft[tid - 256] = ftok[b * 64 + tid - 256];
  else if (tid < 576) st[tid - 320] = stok[b * 256 + tid - 320];
  __syncthreads();
  const int nf = min(cnt[b * 2], 64);
  const int ns = min(cnt[b * 2 + 1], 256);

  {
    const int col = tid & 255, kc = tid >> 8;
    float a = 0.f;
    const float* wp = Wq + (size_t)(kc * 64) * 256 + col;
#pragma unroll 4
    for (int k = 0; k < 64; ++k) a = fmaf(hl[kc * 64 + k], wp[(size_t)k * 256], a);
    qpart[kc][col] = a;
  }
  __syncthreads();
  if (tid < 256)
    q[tid] = ((qpart[0][tid] + qpart[1][tid]) + qpart[2][tid]) + qpart[3][tid] +
             bq[tid];
  __syncthreads();

  const float4 qq = *(const float4*)(q + lane * 4);
#pragma unroll 2
  for (int i = 0; i < 20; ++i) {
    const int r = wv + 16 * i;
    bool valid;
    int tok;
    if (r < 64) { valid = r < nf; tok = valid ? ft[r] : 0; }
    else        { valid = (r - 64) < ns; tok = valid ? st[r - 64] : 0; }
    float sc = NEGV;
    if (valid) {
      const float4 xr = *(const float4*)(Xb + (size_t)tok * 256 + lane * 4);
      float p = (xr.x * qq.x + xr.y * qq.y) + (xr.z * qq.z + xr.w * qq.w);
      sc = dpp_sum63(p);
    }
    if (lane == 63) {
      if (r < 64) sc_f[r] = sc;
      else sc_s[r - 64] = sc;
    }
  }
  __syncthreads();

  if (wv < 4) {
    float s = sc_s[tid];
    float mx = wred_max(s);
    if (lane == 0) redm[wv] = mx;
  } else if (wv == 8) {
    float s = sc_f[lane];
    float mx = wred_max(s);
    float e = expf(s - mx);
    float sm = wred_sum(e);
    float a = e / sm;
    at_f[lane] = a;
    float ma = wred_max(a);
    if (lane == 0) needs_s = (ma < 0.3f) ? 1.f : 0.f;
  }
  __syncthreads();
  if (wv < 4) {
    float s = sc_s[tid];
    float mx = fmaxf(fmaxf(redm[0], redm[1]), fmaxf(redm[2], redm[3]));
    float e = expf(s - mx);
    float sm = wred_sum(e);
    if (lane == 0) reds[wv] = sm;
    at_s[tid] = e;
  }
  __syncthreads();
  if (tid < 256) {
    float sm = (reds[0] + reds[1]) + (reds[2] + reds[3]);
    at_s[tid] = at_s[tid] / sm;
  }
  __syncthreads();

  const float needs = needs_s;
  float4 cp = {0.f, 0.f, 0.f, 0.f};
#pragma unroll 2
  for (int i = 0; i < 20; ++i) {
    const int r = wv + 16 * i;
    bool valid;
    int tok;
    float a;
    if (r < 64) { valid = r < nf; tok = valid ? ft[r] : 0; a = at_f[r]; }
    else {
      valid = (r - 64) < ns;
      tok = valid ? st[r - 64] : 0;
      a = needs * at_s[r - 64];
    }
    if (valid) {
      const float4 xr = *(const float4*)(Xb + (size_t)tok * 256 + lane * 4);
      cp.x = fmaf(a, xr.x, cp.x);
      cp.y = fmaf(a, xr.y, cp.y);
      cp.z = fmaf(a, xr.z, cp.z);
      cp.w = fmaf(a, xr.w, cp.w);
    }
  }
  *(float4*)&cpart[wv][lane * 4] = cp;
  __syncthreads();
  if (tid < 256) {
    float c = 0.f;
#pragma unroll
    for (int w = 0; w < 16; ++w) c += cpart[w][tid];
    ctx[b * 256 + tid] = c;
  }
  if (tid == 0) needs_out[b] = needs;
}

// ---------------- logits: grid 256, XCD-paired (bid & bid+128 same Wo cols)
__global__ __launch_bounds__(256) void logits4_k(
    const float* __restrict__ ctx, const float* __restrict__ Wo,
    const float* __restrict__ bo, float* __restrict__ out) {
  const int bid = blockIdx.x;
  const int xb = bid & 127;
  if (xb >= 125) return;
  const int b0 = (bid >> 7) * 16;
  __shared__ float cs[256 * 16];  // [h][bb]
  const int tid = threadIdx.x;
  for (int i = tid; i < 4096; i += 256) {
    int bb = i & 15, hh = i >> 4;
    cs[hh * 16 + bb] = ctx[(b0 + bb) * 256 + hh];
  }
  __syncthreads();
  const int v = xb * 256 + tid;
  float acc[16];
#pragma unroll
  for (int i = 0; i < 16; ++i) acc[i] = 0.f;
  for (int h0 = 0; h0 < 256; h0 += 16) {
    float wv[16];
#pragma unroll
    for (int u = 0; u < 16; ++u) wv[u] = Wo[(size_t)(h0 + u) * 32000 + v];
#pragma unroll
    for (int u = 0; u < 16; ++u) {
      const float* cp = cs + (h0 + u) * 16;
#pragma unroll
      for (int bb = 0; bb < 16; ++bb) acc[bb] = fmaf(cp[bb], wv[u], acc[bb]);
    }
  }
  float bv = bo[v];
#pragma unroll
  for (int bb = 0; bb < 16; ++bb)
    out[(size_t)(b0 + bb) * 32000 + v] = acc[bb] + bv;
}

extern "C" void kernel_launch(void* const* d_in, const int* in_sizes, int n_in,
                              void* d_out, int out_size, void* d_ws,
                              size_t ws_size, hipStream_t stream) {
  const int* seq = (const int*)d_in[0];
  const float* embed = (const float*)d_in[1];
  const float* W1 = (const float*)d_in[2];
  const float* b1 = (const float*)d_in[3];
  const float* W2 = (const float*)d_in[4];
  const float* b2 = (const float*)d_in[5];
  const float* gamma = (const float*)d_in[6];
  const float* beta = (const float*)d_in[7];
  const float* Wg = (const float*)d_in[8];
  const float* bg = (const float*)d_in[9];
  const float* Wd = (const float*)d_in[10];
  const float* bd = (const float*)d_in[11];
  const float* Wq = (const float*)d_in[12];
  const float* bq = (const float*)d_in[13];
  const float* Wo = (const float*)d_in[14];
  const float* bo = (const float*)d_in[15];
  float* out = (float*)d_out;

  char* wsb = (char*)d_ws;
  // weights + misc first, then act1 h/l (chunk-sized), then X (full)
  ushort* W1th = (ushort*)(wsb);                  // 512*256*2 = 262144
  ushort* W1tl = (ushort*)(wsb + 262144);
  ushort* W2th = (ushort*)(wsb + 524288);         // 256*512*2
  ushort* W2tl = (ushort*)(wsb + 786432);
  int* wbit = (int*)(wsb + 1048576);              // 32768*4
  float* dscp = (float*)(wsb + 1179648);
  int* ftokp = (int*)(wsb + 1310720);
  int* stokp = (int*)(wsb + 1318912);
  int* cntp = (int*)(wsb + 1351680);
  float* ctxp = (float*)(wsb + 1351936);
  const size_t base = 1384704;

  const bool big = ws_size >= (size_t)102100000;
  const int nch = big ? 1 : 2;
  const int rows = 32768 / nch;
  const size_t actsz = (size_t)rows * 512 * 2;
  ushort* act1h = (ushort*)(wsb + base);
  ushort* act1l = (ushort*)(wsb + base + actsz);
  float* X = (float*)(wsb + base + 2 * actsz);

  dim3 blk(256);
  wprep_k<<<dim3(8, 16), blk, 0, stream>>>(W1, W1th, W1tl, 256, 512);
  wprep_k<<<dim3(16, 8), blk, 0, stream>>>(W2, W2th, W2tl, 512, 256);

  for (int c = 0; c < nch; ++c) {
    const int* seqc = seq + c * rows;
    gemm1_k<<<dim3(rows / 128, 4), blk, 0, stream>>>(embed, seqc, W1th, W1tl,
                                                     b1, act1h, act1l);
    gemm2ln_k<<<dim3(rows / 128), dim3(512), 0, stream>>>(
        act1h, act1l, W2th, W2tl, b2, seqc, embed, gamma, beta, Wg, bg, Wd, bd,
        X + (size_t)c * rows * 256, wbit + c * rows, dscp + c * rows);
  }

  select_k<<<32, dim3(1024), 0, stream>>>(wbit, dscp, ftokp, stokp, cntp);
  attn2_k<<<32, dim3(1024), 0, stream>>>(X, Wq, bq, ftokp, stokp, cntp, ctxp,
                                         out + (size_t)32 * 32000);
  logits4_k<<<dim3(256), blk, 0, stream>>>(ctxp, Wo, bo, out);
}

// Round 8
// 180.127 us; speedup vs baseline: 4.0060x; 1.0210x over previous
//
#include <hip/hip_runtime.h>
#include <hip/hip_bf16.h>
#include <cstdint>

#define NEGV -1e9f

typedef __attribute__((ext_vector_type(8))) short short8v;  // 8 bf16 = 4 VGPR
typedef __attribute__((ext_vector_type(4))) float f32x4;

union U8 {
  unsigned u[4];
  short8v v;
};

// ---------------- wave helpers (wave64) ----------------
__device__ __forceinline__ float wred_sum(float v) {
#pragma unroll
  for (int o = 32; o; o >>= 1) v += __shfl_xor(v, o);
  return v;
}
__device__ __forceinline__ float wred_max(float v) {
#pragma unroll
  for (int o = 32; o; o >>= 1) v = fmaxf(v, __shfl_xor(v, o));
  return v;
}
template <int CTRL>
__device__ __forceinline__ float dpp_fadd(float x) {
  int xi = __float_as_int(x);
  int yi = __builtin_amdgcn_update_dpp(xi, xi, CTRL, 0xF, 0xF, false);
  return x + __int_as_float(yi);
}
__device__ __forceinline__ float dpp_sum63(float v) {
  v = dpp_fadd<0xB1>(v);
  v = dpp_fadd<0x4E>(v);
  v = dpp_fadd<0x141>(v);
  v = dpp_fadd<0x140>(v);
  v = dpp_fadd<0x142>(v);
  v = dpp_fadd<0x143>(v);
  return v;  // lane 63 holds the total
}
// 16-lane (DPP-row) sum: every lane of each 16-group gets the group sum.
__device__ __forceinline__ float dpp_sum16(float v) {
  v = dpp_fadd<0xB1>(v);
  v = dpp_fadd<0x4E>(v);
  v = dpp_fadd<0x141>(v);
  v = dpp_fadd<0x140>(v);
  return v;
}

// ---------------- bf16 split helpers (RNE) ----------------
__device__ __forceinline__ ushort bf16hi(float x) {
  unsigned u = __float_as_uint(x);
  unsigned r = u + 0x7FFFu + ((u >> 16) & 1u);
  return (ushort)(r >> 16);
}
__device__ __forceinline__ float bf16tof(ushort u) {
  return __uint_as_float(((unsigned)u) << 16);
}

// async global->LDS, 16B per lane; LDS dest is wave-uniform base + lane*16
__device__ __forceinline__ void gload_lds16(const void* g, void* l) {
  __builtin_amdgcn_global_load_lds(
      (const __attribute__((address_space(1))) unsigned int*)g,
      (__attribute__((address_space(3))) unsigned int*)l, 16, 0, 0);
}

// ---------------- W transpose + split: Wt_h/l[n][k] = split(W[k][n]) -------
__global__ __launch_bounds__(256) void wprep_k(const float* __restrict__ W,
                                               ushort* __restrict__ Wth,
                                               ushort* __restrict__ Wtl,
                                               int K, int N) {
  __shared__ float tile[32][33];
  const int k0 = blockIdx.x * 32, n0 = blockIdx.y * 32;
  const int r = threadIdx.x >> 5, c = threadIdx.x & 31;
#pragma unroll
  for (int i = 0; i < 4; ++i)
    tile[r + i * 8][c] = W[(size_t)(k0 + r + i * 8) * N + n0 + c];
  __syncthreads();
#pragma unroll
  for (int i = 0; i < 4; ++i) {
    const int rn = r + i * 8;
    const float x = tile[c][rn];
    const ushort h = bf16hi(x);
    const ushort l = bf16hi(x - bf16tof(h));
    const size_t o = (size_t)(n0 + rn) * K + k0 + c;
    Wth[o] = h;
    Wtl[o] = l;
  }
}

// ---------------- GEMM1: act1p = pack(split(relu(embed[seq]@W1 + b1))) -----
// split-bf16 3-pass MFMA; 128x256 tile, 8 waves (2m x 4n), BK=64, K=256.
// Output: ONE u32 per element (h | l<<16) -> 64B-coalesced stores (the
// 2-byte/plane stores cost 1.57x write amplification in round 7).
// MFMA order identical to round 7 -> acc bit-identical -> decisions stable.
__global__ __launch_bounds__(512, 1) void gemm1p_k(
    const float* __restrict__ embed, const int* __restrict__ seq,
    const ushort* __restrict__ Bth, const ushort* __restrict__ Btl,
    const float* __restrict__ bias, unsigned* __restrict__ outp) {
  __shared__ alignas(16) ushort Ah[8192], Al[8192];    // 128 x 64
  __shared__ alignas(16) ushort Bh[16384], Bl[16384];  // 256 x 64
  __shared__ int sidx[128];
  const int tid = threadIdx.x;  // 512
  const int m0 = blockIdx.x * 128, n0 = blockIdx.y * 256;
  if (tid < 128) sidx[tid] = seq[m0 + tid];
  __syncthreads();
  const int lane = tid & 63, w = tid >> 6;  // 8 waves
  const int wm = (w >> 2) * 64, wn = (w & 3) * 64;
  const int r15 = lane & 15, khalf = lane >> 4;

  f32x4 acc[4][4];
#pragma unroll
  for (int i = 0; i < 4; ++i)
#pragma unroll
    for (int j = 0; j < 4; ++j) acc[i][j] = (f32x4){0.f, 0.f, 0.f, 0.f};

#pragma unroll 1
  for (int k0 = 0; k0 < 256; k0 += 64) {
    // A: gather fp32 embed rows, split inline (1024 chunks, 2/thread)
#pragma unroll
    for (int i = 0; i < 2; ++i) {
      const int q = tid + i * 512;
      const int row = q >> 3, kq = q & 7;
      const int off = (row * 8 + (kq ^ (row & 7))) * 8;
      const float* ap = embed + (size_t)sidx[row] * 256 + k0 + kq * 8;
      const float4 x0 = *(const float4*)ap;
      const float4 x1 = *(const float4*)(ap + 4);
      const float xs[8] = {x0.x, x0.y, x0.z, x0.w, x1.x, x1.y, x1.z, x1.w};
      short8v vh, vl;
#pragma unroll
      for (int j = 0; j < 8; ++j) {
        const ushort h = bf16hi(xs[j]);
        vh[j] = (short)h;
        vl[j] = (short)bf16hi(xs[j] - bf16tof(h));
      }
      *(short8v*)&Ah[off] = vh;
      *(short8v*)&Al[off] = vl;
    }
    // B: pure copy via global_load_lds (2048 chunks/plane, 4 gload/thread)
#pragma unroll
    for (int i = 0; i < 4; ++i) {
      const int cb = i * 512 + w * 64;
      const int c = cb + lane;
      const int row = c >> 3;
      const int kql = (c & 7) ^ (row & 7);
      const size_t so = (size_t)(n0 + row) * 256 + k0 + kql * 8;
      gload_lds16(Bth + so, &Bh[cb * 8]);
      gload_lds16(Btl + so, &Bl[cb * 8]);
    }
    __syncthreads();
#pragma unroll
    for (int ks = 0; ks < 2; ++ks) {
      const int kq = ks * 4 + khalf;
      short8v ahf[4], alf[4], bhf[4], blf[4];
#pragma unroll
      for (int t = 0; t < 4; ++t) {
        const int ra = wm + t * 16 + r15;
        const int oa = (ra * 8 + (kq ^ (ra & 7))) * 8;
        ahf[t] = *(const short8v*)&Ah[oa];
        alf[t] = *(const short8v*)&Al[oa];
        const int rb = wn + t * 16 + r15;
        const int ob = (rb * 8 + (kq ^ (rb & 7))) * 8;
        bhf[t] = *(const short8v*)&Bh[ob];
        blf[t] = *(const short8v*)&Bl[ob];
      }
#pragma unroll
      for (int mi = 0; mi < 4; ++mi)
#pragma unroll
        for (int ni = 0; ni < 4; ++ni) {
          acc[mi][ni] = __builtin_amdgcn_mfma_f32_16x16x32_bf16(
              ahf[mi], bhf[ni], acc[mi][ni], 0, 0, 0);
          acc[mi][ni] = __builtin_amdgcn_mfma_f32_16x16x32_bf16(
              ahf[mi], blf[ni], acc[mi][ni], 0, 0, 0);
          acc[mi][ni] = __builtin_amdgcn_mfma_f32_16x16x32_bf16(
              alf[mi], bhf[ni], acc[mi][ni], 0, 0, 0);
        }
    }
    __syncthreads();
  }
  // epilogue: relu(acc+b) -> packed u32 (coalesced 64B per 16-lane group)
#pragma unroll
  for (int ni = 0; ni < 4; ++ni) {
    const int n = n0 + wn + ni * 16 + r15;
    const float bv = bias[n];
#pragma unroll
    for (int mi = 0; mi < 4; ++mi) {
      const int mbase = m0 + wm + mi * 16 + khalf * 4;
#pragma unroll
      for (int j = 0; j < 4; ++j) {
        const float t = fmaxf(acc[mi][ni][j] + bv, 0.f);
        const ushort h = bf16hi(t);
        const ushort l = bf16hi(t - bf16tof(h));
        outp[(size_t)(mbase + j) * 512 + n] = (unsigned)h | ((unsigned)l << 16);
      }
    }
  }
}

// ---------------- fused GEMM2 + residual + LayerNorm + gate/dsc ------------
// A from PACKED act1p u32 (h|l<<16): gload_lds to packed LDS, ah/al
// reconstructed in-register (bit-identical values). 128x256 tile, 8 waves.
__global__ __launch_bounds__(512, 1) void gemm2lnp_k(
    const unsigned* __restrict__ Ap, const ushort* __restrict__ Bth,
    const ushort* __restrict__ Btl, const float* __restrict__ b2,
    const int* __restrict__ seq, const float* __restrict__ embed,
    const float* __restrict__ gamma, const float* __restrict__ beta,
    const float* __restrict__ Wg, const float* __restrict__ bg,
    const float* __restrict__ Wd, const float* __restrict__ bd,
    float* __restrict__ X, int* __restrict__ wbit, float* __restrict__ dsc) {
  __shared__ alignas(16) unsigned Alds[8192];          // 128 rows x 16 chunks
  __shared__ alignas(16) ushort Bh[16384], Bl[16384];  // 256 x 64
  __shared__ float par0[128][4], par1[128][4], gpar[128][4], dpar[128][4];
  __shared__ float g_s[256], be_s[256], wg_s[256], wd_s[256], b2_s[256];
  __shared__ int sidx[128];
  const int tid = threadIdx.x;  // 512
  const int m0 = blockIdx.x * 128;
  if (tid < 128) sidx[tid] = seq[m0 + tid];
  if (tid >= 256) {
    const int c = tid - 256;
    g_s[c] = gamma[c];
    be_s[c] = beta[c];
    wg_s[c] = Wg[c];
    wd_s[c] = Wd[c];
    b2_s[c] = b2[c];
  }
  const int lane = tid & 63, w = tid >> 6;  // 8 waves
  const int wm = (w >> 2) * 64, wn = (w & 3) * 64;
  const int r15 = lane & 15, khalf = lane >> 4;

  f32x4 acc[4][4];
#pragma unroll
  for (int i = 0; i < 4; ++i)
#pragma unroll
    for (int j = 0; j < 4; ++j) acc[i][j] = (f32x4){0.f, 0.f, 0.f, 0.f};

#pragma unroll 1
  for (int k0 = 0; k0 < 512; k0 += 64) {
    // A packed: 2048 16B chunks (128 rows x 16), 4 gload/thread
#pragma unroll
    for (int i = 0; i < 4; ++i) {
      const int cb = i * 512 + w * 64;
      const int c = cb + lane;
      const int row = c >> 4, cloc = c & 15;
      const int kc = cloc ^ (row & 15);  // inverse swizzle on source
      const size_t so = (size_t)(m0 + row) * 512 + k0 + kc * 4;
      gload_lds16(Ap + so, &Alds[cb * 4]);
    }
    // B (W2t split planes): 2048 chunks each
#pragma unroll
    for (int i = 0; i < 4; ++i) {
      const int cb = i * 512 + w * 64;
      const int c = cb + lane;
      const int row = c >> 3;
      const int kql = (c & 7) ^ (row & 7);
      const size_t so = (size_t)row * 512 + k0 + kql * 8;
      gload_lds16(Bth + so, &Bh[cb * 8]);
      gload_lds16(Btl + so, &Bl[cb * 8]);
    }
    __syncthreads();
#pragma unroll
    for (int ks = 0; ks < 2; ++ks) {
      const int kq = ks * 4 + khalf;
      short8v ahf[4], alf[4], bhf[4], blf[4];
#pragma unroll
      for (int t = 0; t < 4; ++t) {
        const int ra = wm + t * 16 + r15;
        const int rm = ra & 15;
        const int pc0 = ks * 8 + khalf * 2;
        const uint4 ua = *(const uint4*)&Alds[(ra * 16 + (pc0 ^ rm)) * 4];
        const uint4 ub = *(const uint4*)&Alds[(ra * 16 + ((pc0 + 1) ^ rm)) * 4];
        U8 vh, vl;
        vh.u[0] = (ua.x & 0xffffu) | (ua.y << 16);
        vl.u[0] = (ua.x >> 16) | (ua.y & 0xffff0000u);
        vh.u[1] = (ua.z & 0xffffu) | (ua.w << 16);
        vl.u[1] = (ua.z >> 16) | (ua.w & 0xffff0000u);
        vh.u[2] = (ub.x & 0xffffu) | (ub.y << 16);
        vl.u[2] = (ub.x >> 16) | (ub.y & 0xffff0000u);
        vh.u[3] = (ub.z & 0xffffu) | (ub.w << 16);
        vl.u[3] = (ub.z >> 16) | (ub.w & 0xffff0000u);
        ahf[t] = vh.v;
        alf[t] = vl.v;
        const int rb = wn + t * 16 + r15;
        const int ob = (rb * 8 + (kq ^ (rb & 7))) * 8;
        bhf[t] = *(const short8v*)&Bh[ob];
        blf[t] = *(const short8v*)&Bl[ob];
      }
#pragma unroll
      for (int mi = 0; mi < 4; ++mi)
#pragma unroll
        for (int ni = 0; ni < 4; ++ni) {
          acc[mi][ni] = __builtin_amdgcn_mfma_f32_16x16x32_bf16(
              ahf[mi], bhf[ni], acc[mi][ni], 0, 0, 0);
          acc[mi][ni] = __builtin_amdgcn_mfma_f32_16x16x32_bf16(
              ahf[mi], blf[ni], acc[mi][ni], 0, 0, 0);
          acc[mi][ni] = __builtin_amdgcn_mfma_f32_16x16x32_bf16(
              alf[mi], bhf[ni], acc[mi][ni], 0, 0, 0);
        }
    }
    __syncthreads();
  }

  // ---- epilogue: x = (acc + b2) + resid; then LN + gate/dsc ----
  float mu_r[4][4];
#pragma unroll
  for (int mi = 0; mi < 4; ++mi)
#pragma unroll
    for (int j = 0; j < 4; ++j) {
      const int rowl = wm + mi * 16 + khalf * 4 + j;
      const float* ep = embed + (size_t)sidx[rowl] * 256;
#pragma unroll
      for (int ni = 0; ni < 4; ++ni) {
        const int col = wn + ni * 16 + r15;
        float t = acc[mi][ni][j] + b2_s[col];
        acc[mi][ni][j] = t + ep[col];
      }
      float s = (acc[mi][0][j] + acc[mi][1][j]) + (acc[mi][2][j] + acc[mi][3][j]);
      s = dpp_sum16(s);
      if (r15 == 0) par0[rowl][w & 3] = s;
    }
  __syncthreads();
#pragma unroll
  for (int mi = 0; mi < 4; ++mi)
#pragma unroll
    for (int j = 0; j < 4; ++j) {
      const int rowl = wm + mi * 16 + khalf * 4 + j;
      const float mu = ((par0[rowl][0] + par0[rowl][1]) +
                        (par0[rowl][2] + par0[rowl][3])) * (1.f / 256.f);
      mu_r[mi][j] = mu;
      const float d0 = acc[mi][0][j] - mu, d1 = acc[mi][1][j] - mu;
      const float d2 = acc[mi][2][j] - mu, d3 = acc[mi][3][j] - mu;
      float vv = (d0 * d0 + d1 * d1) + (d2 * d2 + d3 * d3);
      vv = dpp_sum16(vv);
      if (r15 == 0) par1[rowl][w & 3] = vv;
    }
  __syncthreads();
#pragma unroll
  for (int mi = 0; mi < 4; ++mi)
#pragma unroll
    for (int j = 0; j < 4; ++j) {
      const int rowl = wm + mi * 16 + khalf * 4 + j;
      const float mu = mu_r[mi][j];
      const float var = ((par1[rowl][0] + par1[rowl][1]) +
                         (par1[rowl][2] + par1[rowl][3])) * (1.f / 256.f);
      const float rstd = 1.f / sqrtf(var + 1e-5f);
      float ys[4], gw[4], dw[4];
#pragma unroll
      for (int ni = 0; ni < 4; ++ni) {
        const int col = wn + ni * 16 + r15;
        const float y = (acc[mi][ni][j] - mu) * rstd * g_s[col] + be_s[col];
        X[(size_t)(m0 + rowl) * 256 + col] = y;
        ys[ni] = y;
        gw[ni] = wg_s[col];
        dw[ni] = wd_s[col];
      }
      float gp = (ys[0] * gw[0] + ys[1] * gw[1]) + (ys[2] * gw[2] + ys[3] * gw[3]);
      float dp = (ys[0] * dw[0] + ys[1] * dw[1]) + (ys[2] * dw[2] + ys[3] * dw[3]);
      gp = dpp_sum16(gp);
      dp = dpp_sum16(dp);
      if (r15 == 0) {
        gpar[rowl][w & 3] = gp;
        dpar[rowl][w & 3] = dp;
      }
    }
  __syncthreads();
  if (tid < 128) {
    const int row = tid;
    const float gs = ((gpar[row][0] + gpar[row][1]) +
                      (gpar[row][2] + gpar[row][3])) + bg[0];
    const float dsv = ((dpar[row][0] + dpar[row][1]) +
                       (dpar[row][2] + dpar[row][3])) + bd[0];
    float sig;
    if (gs >= 0.f) {
      sig = 1.f / (1.f + expf(-gs));
    } else {
      const float e2 = expf(gs);
      sig = e2 / (1.f + e2);
    }
    wbit[m0 + row] = (sig >= 0.4f) ? 1 : 0;
    dsc[m0 + row] = dsv;
  }
}

// ---------------- offline LRU selection ------------------------------------
// E_k (evicted multiset after k demotions) = k smallest of first 63+k writes.
// fast = last write + 63 largest of first W-1; slow = E_K \ E_{K-256}.
__global__ __launch_bounds__(1024) void select_k(
    const int* __restrict__ wbit, const float* __restrict__ dsc,
    int* __restrict__ ftok, int* __restrict__ stok, int* __restrict__ cnt) {
  const int b = blockIdx.x;
  const int tid = threadIdx.x;
  const int lane = tid & 63, wv = tid >> 6;
  __shared__ unsigned long long skey[1024];
  __shared__ int stokl[1024];
  __shared__ int wavecnt[16];
  __shared__ int waveoff[17];
  __shared__ int fcnt_s[16], scnt_s[16];
  __shared__ int foff[16], soff[16];

  const int t = tid;
  int flag = 0;
  float d = 0.f;
  if (t < 1021) {
    flag = wbit[b * 1024 + t];
    d = dsc[b * 1024 + t];
  }
  const unsigned long long m = __ballot(flag != 0);
  if (lane == 0) wavecnt[wv] = __popcll(m);
  __syncthreads();
  if (tid == 0) {
    int acc = 0;
    for (int i = 0; i < 16; ++i) { waveoff[i] = acc; acc += wavecnt[i]; }
    waveoff[16] = acc;
  }
  __syncthreads();
  const int W = waveoff[16];
  if (flag) {
    unsigned u = __float_as_uint(d);
    u = (u & 0x80000000u) ? ~u : (u | 0x80000000u);
    const int w = waveoff[wv] + __popcll(m & ((1ull << lane) - 1ull));
    skey[w] = ((unsigned long long)u << 32) | (unsigned)w;
    stokl[w] = t;
  }
  __syncthreads();

  const int K = W - 64;
  const int end2 = max(0, W - 257);
  const int endAll = W - 1;
  bool fastf = false, slowf = false;
  if (tid < W) {
    const unsigned long long ki = skey[tid];
    int r1 = 0, r2 = 0;
    int j = 0;
    for (; j < end2; ++j) {
      const int lt = skey[j] < ki;
      r1 += lt;
      r2 += lt;
    }
    for (; j < endAll; ++j) r1 += (skey[j] < ki);
    const bool isLast = (tid == W - 1);
    const bool inEK = (!isLast) && (r1 < K);
    const bool inE2 = (tid < end2) && (r2 < K - 256);
    fastf = isLast || (!isLast && r1 >= K);
    slowf = inEK && !inE2;
  }

  const unsigned long long mf = __ballot(fastf);
  const unsigned long long ms = __ballot(slowf);
  if (lane == 0) { fcnt_s[wv] = __popcll(mf); scnt_s[wv] = __popcll(ms); }
  __syncthreads();
  if (tid == 0) {
    int a = 0, c = 0;
    for (int i = 0; i < 16; ++i) {
      foff[i] = a; a += fcnt_s[i];
      soff[i] = c; c += scnt_s[i];
    }
  }
  __syncthreads();
  if (fastf) {
    const int p = foff[wv] + __popcll(mf & ((1ull << lane) - 1ull));
    ftok[b * 64 + p] = stokl[tid];
  }
  if (slowf) {
    const int p = soff[wv] + __popcll(ms & ((1ull << lane) - 1ull));
    stok[b * 256 + p] = stokl[tid];
  }
  if (tid == 0) {
    cnt[b * 2] = W;
    cnt[b * 2 + 1] = max(K, 0);
  }
}

// ---------------- fused q + dual attention + ctx + need_slow, 16 waves ----
__global__ __launch_bounds__(1024) void attn2_k(
    const float* __restrict__ X, const float* __restrict__ Wq,
    const float* __restrict__ bq, const int* __restrict__ ftok,
    const int* __restrict__ stok, const int* __restrict__ cnt,
    float* __restrict__ ctx, float* __restrict__ needs_out) {
  const int b = blockIdx.x;
  const int tid = threadIdx.x;
  const int lane = tid & 63, wv = tid >> 6;
  __shared__ float hl[256], q[256];
  __shared__ float qpart[4][256];
  __shared__ float sc_f[64], at_f[64];
  __shared__ float sc_s[256], at_s[256];
  __shared__ int ft[64], st[256];
  __shared__ float redm[4], reds[4];
  __shared__ float needs_s;
  __shared__ float cpart[16][256];
  const float* Xb = X + (size_t)b * 1024 * 256;
  if (tid < 256) hl[tid] = Xb[(size_t)1023 * 256 + tid];
  else if (tid < 320) ft[tid - 256] = ftok[b * 64 + tid - 256];
  else if (tid < 576) st[tid - 320] = stok[b * 256 + tid - 320];
  __syncthreads();
  const int nf = min(cnt[b * 2], 64);
  const int ns = min(cnt[b * 2 + 1], 256);

  {
    const int col = tid & 255, kc = tid >> 8;
    float a = 0.f;
    const float* wp = Wq + (size_t)(kc * 64) * 256 + col;
#pragma unroll 4
    for (int k = 0; k < 64; ++k) a = fmaf(hl[kc * 64 + k], wp[(size_t)k * 256], a);
    qpart[kc][col] = a;
  }
  __syncthreads();
  if (tid < 256)
    q[tid] = ((qpart[0][tid] + qpart[1][tid]) + qpart[2][tid]) + qpart[3][tid] +
             bq[tid];
  __syncthreads();

  const float4 qq = *(const float4*)(q + lane * 4);
#pragma unroll 2
  for (int i = 0; i < 20; ++i) {
    const int r = wv + 16 * i;
    bool valid;
    int tok;
    if (r < 64) { valid = r < nf; tok = valid ? ft[r] : 0; }
    else        { valid = (r - 64) < ns; tok = valid ? st[r - 64] : 0; }
    float sc = NEGV;
    if (valid) {
      const float4 xr = *(const float4*)(Xb + (size_t)tok * 256 + lane * 4);
      float p = (xr.x * qq.x + xr.y * qq.y) + (xr.z * qq.z + xr.w * qq.w);
      sc = dpp_sum63(p);
    }
    if (lane == 63) {
      if (r < 64) sc_f[r] = sc;
      else sc_s[r - 64] = sc;
    }
  }
  __syncthreads();

  if (wv < 4) {
    float s = sc_s[tid];
    float mx = wred_max(s);
    if (lane == 0) redm[wv] = mx;
  } else if (wv == 8) {
    float s = sc_f[lane];
    float mx = wred_max(s);
    float e = expf(s - mx);
    float sm = wred_sum(e);
    float a = e / sm;
    at_f[lane] = a;
    float ma = wred_max(a);
    if (lane == 0) needs_s = (ma < 0.3f) ? 1.f : 0.f;
  }
  __syncthreads();
  if (wv < 4) {
    float s = sc_s[tid];
    float mx = fmaxf(fmaxf(redm[0], redm[1]), fmaxf(redm[2], redm[3]));
    float e = expf(s - mx);
    float sm = wred_sum(e);
    if (lane == 0) reds[wv] = sm;
    at_s[tid] = e;
  }
  __syncthreads();
  if (tid < 256) {
    float sm = (reds[0] + reds[1]) + (reds[2] + reds[3]);
    at_s[tid] = at_s[tid] / sm;
  }
  __syncthreads();

  const float needs = needs_s;
  float4 cp = {0.f, 0.f, 0.f, 0.f};
#pragma unroll 2
  for (int i = 0; i < 20; ++i) {
    const int r = wv + 16 * i;
    bool valid;
    int tok;
    float a;
    if (r < 64) { valid = r < nf; tok = valid ? ft[r] : 0; a = at_f[r]; }
    else {
      valid = (r - 64) < ns;
      tok = valid ? st[r - 64] : 0;
      a = needs * at_s[r - 64];
    }
    if (valid) {
      const float4 xr = *(const float4*)(Xb + (size_t)tok * 256 + lane * 4);
      cp.x = fmaf(a, xr.x, cp.x);
      cp.y = fmaf(a, xr.y, cp.y);
      cp.z = fmaf(a, xr.z, cp.z);
      cp.w = fmaf(a, xr.w, cp.w);
    }
  }
  *(float4*)&cpart[wv][lane * 4] = cp;
  __syncthreads();
  if (tid < 256) {
    float c = 0.f;
#pragma unroll
    for (int w = 0; w < 16; ++w) c += cpart[w][tid];
    ctx[b * 256 + tid] = c;
  }
  if (tid == 0) needs_out[b] = needs;
}

// ---------------- logits: grid 256, XCD-paired (bid & bid+128 same Wo cols)
__global__ __launch_bounds__(256) void logits4_k(
    const float* __restrict__ ctx, const float* __restrict__ Wo,
    const float* __restrict__ bo, float* __restrict__ out) {
  const int bid = blockIdx.x;
  const int xb = bid & 127;
  if (xb >= 125) return;
  const int b0 = (bid >> 7) * 16;
  __shared__ float cs[256 * 16];  // [h][bb]
  const int tid = threadIdx.x;
  for (int i = tid; i < 4096; i += 256) {
    int bb = i & 15, hh = i >> 4;
    cs[hh * 16 + bb] = ctx[(b0 + bb) * 256 + hh];
  }
  __syncthreads();
  const int v = xb * 256 + tid;
  float acc[16];
#pragma unroll
  for (int i = 0; i < 16; ++i) acc[i] = 0.f;
  for (int h0 = 0; h0 < 256; h0 += 16) {
    float wv[16];
#pragma unroll
    for (int u = 0; u < 16; ++u) wv[u] = Wo[(size_t)(h0 + u) * 32000 + v];
#pragma unroll
    for (int u = 0; u < 16; ++u) {
      const float* cp = cs + (h0 + u) * 16;
#pragma unroll
      for (int bb = 0; bb < 16; ++bb) acc[bb] = fmaf(cp[bb], wv[u], acc[bb]);
    }
  }
  float bv = bo[v];
#pragma unroll
  for (int bb = 0; bb < 16; ++bb)
    out[(size_t)(b0 + bb) * 32000 + v] = acc[bb] + bv;
}

extern "C" void kernel_launch(void* const* d_in, const int* in_sizes, int n_in,
                              void* d_out, int out_size, void* d_ws,
                              size_t ws_size, hipStream_t stream) {
  const int* seq = (const int*)d_in[0];
  const float* embed = (const float*)d_in[1];
  const float* W1 = (const float*)d_in[2];
  const float* b1 = (const float*)d_in[3];
  const float* W2 = (const float*)d_in[4];
  const float* b2 = (const float*)d_in[5];
  const float* gamma = (const float*)d_in[6];
  const float* beta = (const float*)d_in[7];
  const float* Wg = (const float*)d_in[8];
  const float* bg = (const float*)d_in[9];
  const float* Wd = (const float*)d_in[10];
  const float* bd = (const float*)d_in[11];
  const float* Wq = (const float*)d_in[12];
  const float* bq = (const float*)d_in[13];
  const float* Wo = (const float*)d_in[14];
  const float* bo = (const float*)d_in[15];
  float* out = (float*)d_out;

  char* wsb = (char*)d_ws;
  ushort* W1th = (ushort*)(wsb);                  // 512*256*2 = 262144
  ushort* W1tl = (ushort*)(wsb + 262144);
  ushort* W2th = (ushort*)(wsb + 524288);         // 256*512*2
  ushort* W2tl = (ushort*)(wsb + 786432);
  int* wbit = (int*)(wsb + 1048576);              // 32768*4
  float* dscp = (float*)(wsb + 1179648);
  int* ftokp = (int*)(wsb + 1310720);
  int* stokp = (int*)(wsb + 1318912);
  int* cntp = (int*)(wsb + 1351680);
  float* ctxp = (float*)(wsb + 1351936);
  const size_t base = 1384704;

  const bool big = ws_size >= (size_t)102100000;
  const int nch = big ? 1 : 2;
  const int rows = 32768 / nch;
  const size_t actsz = (size_t)rows * 512 * 4;  // packed u32
  unsigned* act1p = (unsigned*)(wsb + base);
  float* X = (float*)(wsb + base + actsz);

  dim3 blk(256);
  wprep_k<<<dim3(8, 16), blk, 0, stream>>>(W1, W1th, W1tl, 256, 512);
  wprep_k<<<dim3(16, 8), blk, 0, stream>>>(W2, W2th, W2tl, 512, 256);

  for (int c = 0; c < nch; ++c) {
    const int* seqc = seq + c * rows;
    gemm1p_k<<<dim3(rows / 128, 2), dim3(512), 0, stream>>>(
        embed, seqc, W1th, W1tl, b1, act1p);
    gemm2lnp_k<<<dim3(rows / 128), dim3(512), 0, stream>>>(
        act1p, W2th, W2tl, b2, seqc, embed, gamma, beta, Wg, bg, Wd, bd,
        X + (size_t)c * rows * 256, wbit + c * rows, dscp + c * rows);
  }

  select_k<<<32, dim3(1024), 0, stream>>>(wbit, dscp, ftokp, stokp, cntp);
  attn2_k<<<32, dim3(1024), 0, stream>>>(X, Wq, bq, ftokp, stokp, cntp, ctxp,
                                         out + (size_t)32 * 32000);
  logits4_k<<<dim3(256), blk, 0, stream>>>(ctxp, Wo, bo, out);
}